// Round 1
// baseline (2220.757 us; speedup 1.0000x reference)
//
#include <hip/hip_runtime.h>
#include <cstdint>

constexpr int NN   = 30000;
constexpr int NE   = 960000;
constexpr int FIN  = 16;
constexpr int H1   = 36;
constexpr int H2   = 36;
constexpr int KHOP = 8;
constexpr int KSEL = 3000;   // ceil(0.1 * 30000)
constexpr float EPSV = 1e-5f;

#define TPB 256

static inline int nb(long long t) { return (int)((t + TPB - 1) / TPB); }

// ---------------- degree / norm ----------------
__global__ void k_deg(const int* __restrict__ src, float* __restrict__ deg, int E) {
    int e = blockIdx.x * blockDim.x + threadIdx.x;
    if (e < E) atomicAdd(&deg[src[e]], 1.0f);
}

__global__ void k_dinv(float* __restrict__ d, int n) {
    int i = blockIdx.x * blockDim.x + threadIdx.x;
    if (i < n) { float v = d[i]; d[i] = v > 0.f ? 1.0f / sqrtf(v) : 0.0f; }
}

__global__ void k_nnorm(const int* __restrict__ src, const int* __restrict__ dst,
                        const float* __restrict__ dinv, float* __restrict__ nn, int E) {
    int e = blockIdx.x * blockDim.x + threadIdx.x;
    if (e < E) nn[e] = -dinv[src[e]] * dinv[dst[e]];
}

// ---------------- propagation (scatter-atomic) ----------------
template<int F>
__global__ void k_prop(const int* __restrict__ src, const int* __restrict__ dst,
                       const float* __restrict__ nn, const float* __restrict__ h,
                       float* __restrict__ outp, int E) {
    int t = blockIdx.x * blockDim.x + threadIdx.x;
    if (t >= E * F) return;
    int e = t / F, f = t - e * F;
    float v = nn[e] * h[src[e] * F + f];
    atomicAdd(&outp[dst[e] * F + f], v);
}

__global__ void k_combine(const float* __restrict__ P, const float* __restrict__ t0,
                          float* __restrict__ t2, int n) {
    int i = blockIdx.x * blockDim.x + threadIdx.x;
    if (i < n) t2[i] = 2.0f * P[i] - t0[i];
}

// ---------------- small GEMMs ----------------
__global__ void k_bias(const float* __restrict__ b, float* __restrict__ acc, int n, int O) {
    int t = blockIdx.x * blockDim.x + threadIdx.x;
    if (t < n * O) acc[t] = b[t % O];
}

template<int F, int O>
__global__ void k_gemm_acc(const float* __restrict__ in, const float* __restrict__ W,
                           float* __restrict__ acc, int n) {
    __shared__ float sW[F * O];
    for (int i = threadIdx.x; i < F * O; i += blockDim.x) sW[i] = W[i];
    __syncthreads();
    int t = blockIdx.x * blockDim.x + threadIdx.x;
    if (t >= n * O) return;
    int node = t / O, o = t - node * O;
    const float* r = &in[node * F];
    float s = 0.f;
#pragma unroll
    for (int f = 0; f < F; ++f) s = fmaf(r[f], sW[f * O + o], s);
    acc[t] += s;
}

// ---------------- relu + batchnorm ----------------
template<int C>
__global__ void k_colstats(const float* __restrict__ a, float* __restrict__ stats, int n) {
    __shared__ float s1[C], s2[C];
    for (int i = threadIdx.x; i < C; i += blockDim.x) { s1[i] = 0.f; s2[i] = 0.f; }
    __syncthreads();
    int total = n * C, stride = gridDim.x * blockDim.x;
    for (int t = blockIdx.x * blockDim.x + threadIdx.x; t < total; t += stride) {
        float v = fmaxf(a[t], 0.f); int c = t % C;
        atomicAdd(&s1[c], v); atomicAdd(&s2[c], v * v);
    }
    __syncthreads();
    for (int i = threadIdx.x; i < C; i += blockDim.x) {
        atomicAdd(&stats[i], s1[i]); atomicAdd(&stats[C + i], s2[i]);
    }
}

template<int C>
__global__ void k_bn(const float* __restrict__ a, const float* __restrict__ stats,
                     const float* __restrict__ g, const float* __restrict__ be,
                     float* __restrict__ o, int n) {
    int t = blockIdx.x * blockDim.x + threadIdx.x;
    if (t >= n * C) return;
    int c = t % C;
    float mu = stats[c] / n;
    float var = stats[C + c] / n - mu * mu;
    float v = fmaxf(a[t], 0.f);
    o[t] = (v - mu) * rsqrtf(var + EPSV) * g[c] + be[c];
}

// ---------------- xc, score, sortable key ----------------
__global__ void k_xc_score(const float* __restrict__ x1, const float* __restrict__ Wc,
                           const float* __restrict__ bc, const float* __restrict__ pw,
                           float* __restrict__ xc, float* __restrict__ score,
                           unsigned* __restrict__ key, int n) {
    int i = blockIdx.x * blockDim.x + threadIdx.x;
    if (i >= n) return;
    const float* r = &x1[i * H1];
    float a = bc[0], b = bc[1];
#pragma unroll
    for (int f = 0; f < H1; ++f) { float v = r[f]; a = fmaf(v, Wc[f * 2], a); b = fmaf(v, Wc[f * 2 + 1], b); }
    xc[i * 2] = a; xc[i * 2 + 1] = b;
    float w0 = pw[0], w1 = pw[1];
    float s = tanhf((a * w0 + b * w1) / sqrtf(w0 * w0 + w1 * w1));
    score[i] = s;
    unsigned u = __float_as_uint(s);
    key[i] = (u & 0x80000000u) ? ~u : (u | 0x80000000u);
}

// ---------------- radix select: T = k-th largest key, r = #(==T) to take ----------------
__global__ void k_kth(const unsigned* __restrict__ key, int n, int k,
                      unsigned* __restrict__ outT, int* __restrict__ outR) {
    __shared__ int hist[256];
    __shared__ unsigned sprefix;
    __shared__ int skrem;
    int tid = threadIdx.x;
    if (tid == 0) { sprefix = 0u; skrem = k; }
    for (int pass = 3; pass >= 0; --pass) {
        __syncthreads();
        for (int i = tid; i < 256; i += blockDim.x) hist[i] = 0;
        __syncthreads();
        unsigned pref = sprefix;
        int shift = (pass + 1) * 8;
        for (int i = tid; i < n; i += blockDim.x) {
            unsigned kk = key[i];
            bool match = ((unsigned long long)kk >> shift) == ((unsigned long long)pref >> shift);
            if (match) atomicAdd(&hist[(kk >> (pass * 8)) & 0xFF], 1);
        }
        __syncthreads();
        if (tid == 0) {
            int krem = skrem;
            int cum = 0; int d = 0;
            for (int b = 255; b >= 0; --b) {
                if (cum + hist[b] >= krem) { d = b; break; }
                cum += hist[b];
            }
            sprefix |= ((unsigned)d) << (pass * 8);
            skrem = krem - cum;
        }
    }
    __syncthreads();
    if (tid == 0) { *outT = sprefix; *outR = skrem; }
}

// ---------------- deterministic top-k selection (index-ordered) ----------------
__device__ __forceinline__ int block_scan_excl_1024(int val, int& total) {
    __shared__ int wsum[16];
    int tid = threadIdx.x, lane = tid & 63, wv = tid >> 6;
    int v = val;
#pragma unroll
    for (int off = 1; off < 64; off <<= 1) {
        int t = __shfl_up(v, off, 64);
        if (lane >= off) v += t;
    }
    __syncthreads();
    if (lane == 63) wsum[wv] = v;
    __syncthreads();
    if (tid < 16) {
        int w = wsum[tid];
#pragma unroll
        for (int off = 1; off < 16; off <<= 1) {
            int t = __shfl_up(w, off, 64);
            if (tid >= off) w += t;
        }
        wsum[tid] = w;
    }
    __syncthreads();
    int base = (wv > 0) ? wsum[wv - 1] : 0;
    total = wsum[15];
    return base + v - val;
}

__global__ void k_select(const unsigned* __restrict__ key, const unsigned* __restrict__ pT,
                         const int* __restrict__ pR, int* __restrict__ nidx,
                         int* __restrict__ sel, int n) {
    unsigned T = *pT; int r = *pR;
    __shared__ int run_sel, run_eq;
    if (threadIdx.x == 0) { run_sel = 0; run_eq = 0; }
    __syncthreads();
    for (int base = 0; base < n; base += 1024) {
        int i = base + threadIdx.x;
        unsigned kk = (i < n) ? key[i] : 0u;
        int eq = (i < n && kk == T) ? 1 : 0;
        int gt = (i < n && kk > T) ? 1 : 0;
        int eq_tot; int eq_ex = block_scan_excl_1024(eq, eq_tot);
        int re = run_eq;
        int sf = gt | (eq & (((re + eq_ex) < r) ? 1 : 0));
        int s_tot; int s_ex = block_scan_excl_1024(sf, s_tot);
        int rs = run_sel;
        if (i < n) {
            if (sf) { int slot = rs + s_ex; nidx[i] = slot; sel[slot] = i; }
            else nidx[i] = -1;
        }
        __syncthreads();
        if (threadIdx.x == 0) { run_sel = rs + s_tot; run_eq = re + eq_tot; }
        __syncthreads();
    }
}

__global__ void k_gather(const int* __restrict__ sel, const float* __restrict__ x,
                         const float* __restrict__ xc, const float* __restrict__ score,
                         float* __restrict__ selpos, float* __restrict__ xp1, int k) {
    int j = blockIdx.x * blockDim.x + threadIdx.x;
    if (j >= k) return;
    int i = sel[j];
    selpos[j * 2]     = x[i * FIN + 14];
    selpos[j * 2 + 1] = x[i * FIN + 15];
    float s = score[i];
    xp1[j * 2]     = xc[i * 2] * s;
    xp1[j * 2 + 1] = xc[i * 2 + 1] * s;
}

// ---------------- pooled graph ----------------
__global__ void k_degp(const int* __restrict__ src, const int* __restrict__ dst,
                       const int* __restrict__ nidx, float* __restrict__ degp, int E) {
    int e = blockIdx.x * blockDim.x + threadIdx.x;
    if (e >= E) return;
    int vs = nidx[src[e]], vd = nidx[dst[e]];
    if (vs >= 0 && vd >= 0) atomicAdd(&degp[vs], 1.0f);
}

__global__ void k_propp(const int* __restrict__ src, const int* __restrict__ dst,
                        const int* __restrict__ nidx, const float* __restrict__ dinvp,
                        const float* __restrict__ h, float* __restrict__ o, int E) {
    int e = blockIdx.x * blockDim.x + threadIdx.x;
    if (e >= E) return;
    int vs = nidx[src[e]], vd = nidx[dst[e]];
    if (vs < 0 || vd < 0) return;
    float w = -dinvp[vs] * dinvp[vd];
    atomicAdd(&o[vd * 2],     w * h[vs * 2]);
    atomicAdd(&o[vd * 2 + 1], w * h[vs * 2 + 1]);
}

// ---------------- nearest pooled node (2D argmin) ----------------
__global__ void k_nearest(const float* __restrict__ x, const float* __restrict__ selpos,
                          int* __restrict__ nearest, int n, int k) {
    __shared__ float sp[KSEL * 2];
    for (int j = threadIdx.x; j < k * 2; j += blockDim.x) sp[j] = selpos[j];
    __syncthreads();
    int i = blockIdx.x * blockDim.x + threadIdx.x;
    if (i >= n) return;
    float px = x[i * FIN + 14], py = x[i * FIN + 15];
    float best = 3.4e38f; int bj = 0;
    for (int j = 0; j < k; ++j) {
        float dx = px - sp[j * 2], dy = py - sp[j * 2 + 1];
        float d = dx * dx + dy * dy;
        if (d < best) { best = d; bj = j; }
    }
    nearest[i] = bj;
}

// ---------------- final linear (74 -> 10) ----------------
__global__ void k_final(const float* __restrict__ x1, const float* __restrict__ x2,
                        const float* __restrict__ xp2, const int* __restrict__ nearest,
                        const float* __restrict__ W3, const float* __restrict__ b3,
                        float* __restrict__ o, int n) {
    __shared__ float sW[740], sb[10];
    for (int i = threadIdx.x; i < 740; i += blockDim.x) sW[i] = W3[i];
    if (threadIdx.x < 10) sb[threadIdx.x] = b3[threadIdx.x];
    __syncthreads();
    int t = blockIdx.x * blockDim.x + threadIdx.x;
    if (t >= n * 10) return;
    int i = t / 10, c = t - 10 * (t / 10);
    float s = sb[c];
    const float* r1 = &x1[i * H1];
#pragma unroll
    for (int f = 0; f < H1; ++f) s = fmaf(r1[f], sW[f * 10 + c], s);
    const float* r2 = &x2[i * H2];
#pragma unroll
    for (int f = 0; f < H2; ++f) s = fmaf(r2[f], sW[(H1 + f) * 10 + c], s);
    int m = nearest[i];
    s = fmaf(xp2[m * 2],     sW[720 + c], s);
    s = fmaf(xp2[m * 2 + 1], sW[730 + c], s);
    o[t] = s;
}

// =====================================================================
extern "C" void kernel_launch(void* const* d_in, const int* in_sizes, int n_in,
                              void* d_out, int out_size, void* d_ws, size_t ws_size,
                              hipStream_t stream) {
    const float* x   = (const float*)d_in[0];
    const int*   ei  = (const int*)d_in[1];
    const int*   src = ei;
    const int*   dst = ei + NE;
    const float* W1  = (const float*)d_in[2];
    const float* b1  = (const float*)d_in[3];
    const float* W2  = (const float*)d_in[4];
    const float* b2  = (const float*)d_in[5];
    const float* g1  = (const float*)d_in[6];
    const float* be1 = (const float*)d_in[7];
    const float* g2  = (const float*)d_in[8];
    const float* be2 = (const float*)d_in[9];
    const float* Wc  = (const float*)d_in[10];
    const float* bc  = (const float*)d_in[11];
    const float* pw  = (const float*)d_in[12];
    const float* Wp  = (const float*)d_in[13];
    const float* bp  = (const float*)d_in[14];
    const float* W3  = (const float*)d_in[15];
    const float* b3  = (const float*)d_in[16];
    float* out = (float*)d_out;

    // ---- workspace layout ----
    char* w = (char*)d_ws;
    auto alloc = [&](size_t bytes) -> void* {
        void* p = (void*)w;
        w += (bytes + 255) & ~(size_t)255;
        return p;
    };
    float* deg   = (float*)alloc(NN * 4);
    float* nnorm = (float*)alloc((size_t)NE * 4);
    float* B1    = (float*)alloc((size_t)NN * H1 * 4);
    float* B2    = (float*)alloc((size_t)NN * H1 * 4);
    float* B3    = (float*)alloc((size_t)NN * H1 * 4);
    float* acc   = (float*)alloc((size_t)NN * H1 * 4);
    float* x1    = (float*)alloc((size_t)NN * H1 * 4);
    float* x2    = (float*)alloc((size_t)NN * H2 * 4);
    float* xc    = (float*)alloc((size_t)NN * 2 * 4);
    float* score = (float*)alloc(NN * 4);
    float* stats = (float*)alloc(2 * H1 * 4);
    float* xp1   = (float*)alloc(KSEL * 2 * 4);
    float* P1    = (float*)alloc(KSEL * 2 * 4);
    float* P2    = (float*)alloc(KSEL * 2 * 4);
    float* P3    = (float*)alloc(KSEL * 2 * 4);
    float* pacc  = (float*)alloc(KSEL * 2 * 4);
    float* degp  = (float*)alloc(KSEL * 4);
    float* selpos= (float*)alloc(KSEL * 2 * 4);
    unsigned* key   = (unsigned*)alloc(NN * 4);
    int* nidx       = (int*)alloc(NN * 4);
    int* sel        = (int*)alloc(KSEL * 4);
    int* nearest    = (int*)alloc(NN * 4);
    unsigned* Tptr  = (unsigned*)alloc(4);
    int* Rptr       = (int*)alloc(4);

    // ---- degree / norm (main graph) ----
    hipMemsetAsync(deg, 0, NN * 4, stream);
    k_deg<<<nb(NE), TPB, 0, stream>>>(src, deg, NE);
    k_dinv<<<nb(NN), TPB, 0, stream>>>(deg, NN);
    k_nnorm<<<nb(NE), TPB, 0, stream>>>(src, dst, deg, nnorm, NE);

    // ---- conv1: K=8, 16 -> 36 ----
    {
        k_bias<<<nb((long long)NN * H1), TPB, 0, stream>>>(b1, acc, NN, H1);
        k_gemm_acc<FIN, H1><<<nb((long long)NN * H1), TPB, 0, stream>>>(x, W1, acc, NN);
        const float* prev = x; const float* cur;
        float* bufs[3] = {B1, B2, B3}; int bi = 0;
        {
            float* P = bufs[bi]; bi = (bi + 1) % 3;
            hipMemsetAsync(P, 0, (size_t)NN * FIN * 4, stream);
            k_prop<FIN><<<nb((long long)NE * FIN), TPB, 0, stream>>>(src, dst, nnorm, prev, P, NE);
            cur = P;
            k_gemm_acc<FIN, H1><<<nb((long long)NN * H1), TPB, 0, stream>>>(cur, W1 + FIN * H1, acc, NN);
        }
        for (int kk = 2; kk < KHOP; ++kk) {
            float* Q = bufs[bi]; bi = (bi + 1) % 3;
            hipMemsetAsync(Q, 0, (size_t)NN * FIN * 4, stream);
            k_prop<FIN><<<nb((long long)NE * FIN), TPB, 0, stream>>>(src, dst, nnorm, cur, Q, NE);
            k_combine<<<nb((long long)NN * FIN), TPB, 0, stream>>>(Q, prev, Q, NN * FIN);
            prev = cur; cur = Q;
            k_gemm_acc<FIN, H1><<<nb((long long)NN * H1), TPB, 0, stream>>>(cur, W1 + kk * FIN * H1, acc, NN);
        }
        hipMemsetAsync(stats, 0, 2 * H1 * 4, stream);
        k_colstats<H1><<<120, TPB, 0, stream>>>(acc, stats, NN);
        k_bn<H1><<<nb((long long)NN * H1), TPB, 0, stream>>>(acc, stats, g1, be1, x1, NN);
    }

    // ---- conv2: K=8, 36 -> 36 ----
    {
        k_bias<<<nb((long long)NN * H2), TPB, 0, stream>>>(b2, acc, NN, H2);
        k_gemm_acc<H1, H2><<<nb((long long)NN * H2), TPB, 0, stream>>>(x1, W2, acc, NN);
        const float* prev = x1; const float* cur;
        float* bufs[3] = {B1, B2, B3}; int bi = 0;
        {
            float* P = bufs[bi]; bi = (bi + 1) % 3;
            hipMemsetAsync(P, 0, (size_t)NN * H1 * 4, stream);
            k_prop<H1><<<nb((long long)NE * H1), TPB, 0, stream>>>(src, dst, nnorm, prev, P, NE);
            cur = P;
            k_gemm_acc<H1, H2><<<nb((long long)NN * H2), TPB, 0, stream>>>(cur, W2 + H1 * H2, acc, NN);
        }
        for (int kk = 2; kk < KHOP; ++kk) {
            float* Q = bufs[bi]; bi = (bi + 1) % 3;
            hipMemsetAsync(Q, 0, (size_t)NN * H1 * 4, stream);
            k_prop<H1><<<nb((long long)NE * H1), TPB, 0, stream>>>(src, dst, nnorm, cur, Q, NE);
            k_combine<<<nb((long long)NN * H1), TPB, 0, stream>>>(Q, prev, Q, NN * H1);
            prev = cur; cur = Q;
            k_gemm_acc<H1, H2><<<nb((long long)NN * H2), TPB, 0, stream>>>(cur, W2 + kk * H1 * H2, acc, NN);
        }
        hipMemsetAsync(stats, 0, 2 * H2 * 4, stream);
        k_colstats<H2><<<120, TPB, 0, stream>>>(acc, stats, NN);
        k_bn<H2><<<nb((long long)NN * H2), TPB, 0, stream>>>(acc, stats, g2, be2, x2, NN);
    }

    // ---- xc (K=1, 36->2), score, key ----
    k_xc_score<<<nb(NN), TPB, 0, stream>>>(x1, Wc, bc, pw, xc, score, key, NN);

    // ---- top-k selection ----
    k_kth<<<1, 256, 0, stream>>>(key, NN, KSEL, Tptr, Rptr);
    k_select<<<1, 1024, 0, stream>>>(key, Tptr, Rptr, nidx, sel, NN);
    k_gather<<<nb(KSEL), TPB, 0, stream>>>(sel, x, xc, score, selpos, xp1, KSEL);

    // ---- pooled graph degree ----
    hipMemsetAsync(degp, 0, KSEL * 4, stream);
    k_degp<<<nb(NE), TPB, 0, stream>>>(src, dst, nidx, degp, NE);
    k_dinv<<<nb(KSEL), TPB, 0, stream>>>(degp, KSEL);

    // ---- pooled conv: K=8, 2 -> 2 ----
    {
        k_bias<<<nb((long long)KSEL * 2), TPB, 0, stream>>>(bp, pacc, KSEL, 2);
        k_gemm_acc<2, 2><<<nb((long long)KSEL * 2), TPB, 0, stream>>>(xp1, Wp, pacc, KSEL);
        const float* prev = xp1; const float* cur;
        float* bufs[3] = {P1, P2, P3}; int bi = 0;
        {
            float* P = bufs[bi]; bi = (bi + 1) % 3;
            hipMemsetAsync(P, 0, KSEL * 2 * 4, stream);
            k_propp<<<nb(NE), TPB, 0, stream>>>(src, dst, nidx, degp, prev, P, NE);
            cur = P;
            k_gemm_acc<2, 2><<<nb((long long)KSEL * 2), TPB, 0, stream>>>(cur, Wp + 4, pacc, KSEL);
        }
        for (int kk = 2; kk < KHOP; ++kk) {
            float* Q = bufs[bi]; bi = (bi + 1) % 3;
            hipMemsetAsync(Q, 0, KSEL * 2 * 4, stream);
            k_propp<<<nb(NE), TPB, 0, stream>>>(src, dst, nidx, degp, cur, Q, NE);
            k_combine<<<nb((long long)KSEL * 2), TPB, 0, stream>>>(Q, prev, Q, KSEL * 2);
            prev = cur; cur = Q;
            k_gemm_acc<2, 2><<<nb((long long)KSEL * 2), TPB, 0, stream>>>(cur, Wp + kk * 4, pacc, KSEL);
        }
    }

    // ---- nearest pooled node, final linear ----
    k_nearest<<<nb(NN), TPB, 0, stream>>>(x, selpos, nearest, NN, KSEL);
    k_final<<<nb((long long)NN * 10), TPB, 0, stream>>>(x1, x2, pacc, nearest, W3, b3, out, NN);
}

// Round 2
// 1447.683 us; speedup vs baseline: 1.5340x; 1.5340x over previous
//
#include <hip/hip_runtime.h>
#include <cstdint>

constexpr int NN   = 30000;
constexpr int NE   = 960000;
constexpr int FIN  = 16;
constexpr int H1   = 36;
constexpr int H2   = 36;
constexpr int KHOP = 8;
constexpr int KSEL = 3000;   // ceil(0.1 * 30000)
constexpr int PCAP = 32768;  // pooled-edge capacity (expected ~9600)
constexpr float EPSV = 1e-5f;

#define TPB 256

static inline int nb(long long t) { return (int)((t + TPB - 1) / TPB); }

// L2-coherent load/store (bypass L1; atomics land in L2)
__device__ __forceinline__ float AL(const float* p) {
    return __hip_atomic_load(p, __ATOMIC_RELAXED, __HIP_MEMORY_SCOPE_AGENT);
}
__device__ __forceinline__ void AS(float* p, float v) {
    __hip_atomic_store(p, v, __ATOMIC_RELAXED, __HIP_MEMORY_SCOPE_AGENT);
}

// ---------------- degree counting (src for norm, dst for CSR) ----------------
__global__ void k_count2(const int* __restrict__ src, const int* __restrict__ dst,
                         int* __restrict__ cnt_src, int* __restrict__ cnt_dst, int E) {
    int e = blockIdx.x * blockDim.x + threadIdx.x;
    if (e >= E) return;
    atomicAdd(&cnt_src[src[e]], 1);
    atomicAdd(&cnt_dst[dst[e]], 1);
}

__global__ void k_dinv2(const int* __restrict__ cnt, float* __restrict__ dinv, int n) {
    int i = blockIdx.x * blockDim.x + threadIdx.x;
    if (i < n) { int v = cnt[i]; dinv[i] = v > 0 ? rsqrtf((float)v) : 0.0f; }
}

// ---------------- block scan helper (blockDim must be 1024) ----------------
__device__ __forceinline__ int block_scan_excl_1024(int val, int& total) {
    __shared__ int wsum[16];
    int tid = threadIdx.x, lane = tid & 63, wv = tid >> 6;
    int v = val;
#pragma unroll
    for (int off = 1; off < 64; off <<= 1) {
        int t = __shfl_up(v, off, 64);
        if (lane >= off) v += t;
    }
    __syncthreads();
    if (lane == 63) wsum[wv] = v;
    __syncthreads();
    if (tid < 16) {
        int w = wsum[tid];
#pragma unroll
        for (int off = 1; off < 16; off <<= 1) {
            int t = __shfl_up(w, off, 64);
            if (tid >= off) w += t;
        }
        wsum[tid] = w;
    }
    __syncthreads();
    int base = (wv > 0) ? wsum[wv - 1] : 0;
    total = wsum[15];
    return base + v - val;
}

__global__ void k_scan(const int* __restrict__ cnt, int* __restrict__ rowstart, int n) {
    __shared__ int run;
    if (threadIdx.x == 0) run = 0;
    __syncthreads();
    for (int base = 0; base < n; base += 1024) {
        int i = base + threadIdx.x;
        int v = (i < n) ? cnt[i] : 0;
        int tot; int ex = block_scan_excl_1024(v, tot);
        int r = run;
        if (i < n) rowstart[i] = r + ex;
        __syncthreads();
        if (threadIdx.x == 0) run += tot;
        __syncthreads();
    }
    if (threadIdx.x == 0) rowstart[n] = run;
}

// ---------------- CSR fill: (src, norm-weight) pairs grouped by dst ----------------
__global__ void k_fill(const int* __restrict__ src, const int* __restrict__ dst,
                       const float* __restrict__ dinv, const int* __restrict__ rowstart,
                       int* __restrict__ cursor, int2* __restrict__ csr, int E) {
    int e = blockIdx.x * blockDim.x + threadIdx.x;
    if (e >= E) return;
    int s = src[e], d = dst[e];
    int pos = atomicAdd(&cursor[d], 1);
    float w = -dinv[s] * dinv[d];
    csr[rowstart[d] + pos] = make_int2(s, __float_as_int(w));
}

// ---------------- acc = b + in @ W[0] ----------------
template<int F, int O>
__global__ void k_gemm_init(const float* __restrict__ in, const float* __restrict__ W,
                            const float* __restrict__ b, float* __restrict__ acc, int n) {
    __shared__ float sW[F * O];
    for (int i = threadIdx.x; i < F * O; i += blockDim.x) sW[i] = W[i];
    __syncthreads();
    int t = blockIdx.x * blockDim.x + threadIdx.x;
    if (t >= n * O) return;
    int node = t / O, o = t - node * O;
    const float* r = &in[node * F];
    float s = b[o];
#pragma unroll
    for (int f = 0; f < F; ++f) s = fmaf(r[f], sW[f * O + o], s);
    acc[t] = s;
}

// ---------------- fused: t_k = (2?)*(-Ahat h) - t0 ; tout=t_k ; acc += t_k @ W ----------------
template<int F, int O, int BN>
__global__ __launch_bounds__(BN * F / 4)
void k_prop_gemm(const int* __restrict__ rowstart, const int2* __restrict__ csr,
                 const float* __restrict__ h, const float* __restrict__ t0,
                 const float* __restrict__ W, float* __restrict__ tout,
                 float* __restrict__ acc, int n, int first) {
    constexpr int QF = F / 4;
    constexpr int NT = BN * QF;
    __shared__ float sT[BN * F];
    __shared__ float sW[F * O];
    const int tid = threadIdx.x;
    for (int i = tid; i < F * O; i += NT) sW[i] = W[i];
    const int nl = tid / QF, q = tid - nl * QF;
    const int node = blockIdx.x * BN + nl;
    if (node < n) {
        const float4* __restrict__ h4 = (const float4*)h;
        float4 p = {0.f, 0.f, 0.f, 0.f};
        int e0 = rowstart[node], e1 = rowstart[node + 1];
        for (int e = e0; e < e1; ++e) {
            int2 ew = csr[e];
            float w = __int_as_float(ew.y);
            float4 hv = h4[ew.x * QF + q];
            p.x = fmaf(w, hv.x, p.x); p.y = fmaf(w, hv.y, p.y);
            p.z = fmaf(w, hv.z, p.z); p.w = fmaf(w, hv.w, p.w);
        }
        if (!first) {
            float4 tv = ((const float4*)t0)[node * QF + q];
            p.x = 2.f * p.x - tv.x; p.y = 2.f * p.y - tv.y;
            p.z = 2.f * p.z - tv.z; p.w = 2.f * p.w - tv.w;
        }
        ((float4*)tout)[node * QF + q] = p;
        sT[nl * F + 4 * q + 0] = p.x; sT[nl * F + 4 * q + 1] = p.y;
        sT[nl * F + 4 * q + 2] = p.z; sT[nl * F + 4 * q + 3] = p.w;
    }
    __syncthreads();
    for (int idx = tid; idx < BN * O; idx += NT) {
        int nl2 = idx / O, o = idx - nl2 * O;
        int gn = blockIdx.x * BN + nl2;
        if (gn >= n) break;
        float s = 0.f;
#pragma unroll
        for (int f = 0; f < F; ++f) s = fmaf(sT[nl2 * F + f], sW[f * O + o], s);
        acc[gn * O + o] += s;
    }
}

// ---------------- relu + batchnorm ----------------
template<int C>
__global__ void k_colstats(const float* __restrict__ a, float* __restrict__ stats, int n) {
    __shared__ float s1[C], s2[C];
    for (int i = threadIdx.x; i < C; i += blockDim.x) { s1[i] = 0.f; s2[i] = 0.f; }
    __syncthreads();
    int total = n * C, stride = gridDim.x * blockDim.x;
    for (int t = blockIdx.x * blockDim.x + threadIdx.x; t < total; t += stride) {
        float v = fmaxf(a[t], 0.f); int c = t % C;
        atomicAdd(&s1[c], v); atomicAdd(&s2[c], v * v);
    }
    __syncthreads();
    for (int i = threadIdx.x; i < C; i += blockDim.x) {
        atomicAdd(&stats[i], s1[i]); atomicAdd(&stats[C + i], s2[i]);
    }
}

template<int C>
__global__ void k_bn(const float* __restrict__ a, const float* __restrict__ stats,
                     const float* __restrict__ g, const float* __restrict__ be,
                     float* __restrict__ o, int n) {
    int t = blockIdx.x * blockDim.x + threadIdx.x;
    if (t >= n * C) return;
    int c = t % C;
    float mu = stats[c] / n;
    float var = stats[C + c] / n - mu * mu;
    float v = fmaxf(a[t], 0.f);
    o[t] = (v - mu) * rsqrtf(var + EPSV) * g[c] + be[c];
}

// ---------------- xc, score, sortable key ----------------
__global__ void k_xc_score(const float* __restrict__ x1, const float* __restrict__ Wc,
                           const float* __restrict__ bc, const float* __restrict__ pw,
                           float* __restrict__ xc, float* __restrict__ score,
                           unsigned* __restrict__ key, int n) {
    int i = blockIdx.x * blockDim.x + threadIdx.x;
    if (i >= n) return;
    const float* r = &x1[i * H1];
    float a = bc[0], b = bc[1];
#pragma unroll
    for (int f = 0; f < H1; ++f) { float v = r[f]; a = fmaf(v, Wc[f * 2], a); b = fmaf(v, Wc[f * 2 + 1], b); }
    xc[i * 2] = a; xc[i * 2 + 1] = b;
    float w0 = pw[0], w1 = pw[1];
    float s = tanhf((a * w0 + b * w1) / sqrtf(w0 * w0 + w1 * w1));
    score[i] = s;
    unsigned u = __float_as_uint(s);
    key[i] = (u & 0x80000000u) ? ~u : (u | 0x80000000u);
}

// ---------------- radix select: T = k-th largest key, r = #(==T) to take ----------------
__global__ void k_kth(const unsigned* __restrict__ key, int n, int k,
                      unsigned* __restrict__ outT, int* __restrict__ outR) {
    __shared__ int hist[256];
    __shared__ unsigned sprefix;
    __shared__ int skrem;
    int tid = threadIdx.x;
    if (tid == 0) { sprefix = 0u; skrem = k; }
    for (int pass = 3; pass >= 0; --pass) {
        __syncthreads();
        for (int i = tid; i < 256; i += blockDim.x) hist[i] = 0;
        __syncthreads();
        unsigned pref = sprefix;
        int shift = (pass + 1) * 8;
        for (int i = tid; i < n; i += blockDim.x) {
            unsigned kk = key[i];
            bool match = ((unsigned long long)kk >> shift) == ((unsigned long long)pref >> shift);
            if (match) atomicAdd(&hist[(kk >> (pass * 8)) & 0xFF], 1);
        }
        __syncthreads();
        if (tid == 0) {
            int krem = skrem;
            int cum = 0; int d = 0;
            for (int b = 255; b >= 0; --b) {
                if (cum + hist[b] >= krem) { d = b; break; }
                cum += hist[b];
            }
            sprefix |= ((unsigned)d) << (pass * 8);
            skrem = krem - cum;
        }
    }
    __syncthreads();
    if (tid == 0) { *outT = sprefix; *outR = skrem; }
}

__global__ void k_select(const unsigned* __restrict__ key, const unsigned* __restrict__ pT,
                         const int* __restrict__ pR, int* __restrict__ nidx,
                         int* __restrict__ sel, int n) {
    unsigned T = *pT; int r = *pR;
    __shared__ int run_sel, run_eq;
    if (threadIdx.x == 0) { run_sel = 0; run_eq = 0; }
    __syncthreads();
    for (int base = 0; base < n; base += 1024) {
        int i = base + threadIdx.x;
        unsigned kk = (i < n) ? key[i] : 0u;
        int eq = (i < n && kk == T) ? 1 : 0;
        int gt = (i < n && kk > T) ? 1 : 0;
        int eq_tot; int eq_ex = block_scan_excl_1024(eq, eq_tot);
        int re = run_eq;
        int sf = gt | (eq & (((re + eq_ex) < r) ? 1 : 0));
        int s_tot; int s_ex = block_scan_excl_1024(sf, s_tot);
        int rs = run_sel;
        if (i < n) {
            if (sf) { int slot = rs + s_ex; nidx[i] = slot; sel[slot] = i; }
            else nidx[i] = -1;
        }
        __syncthreads();
        if (threadIdx.x == 0) { run_sel = rs + s_tot; run_eq = re + eq_tot; }
        __syncthreads();
    }
}

// ---------------- compact pooled edges ----------------
__global__ void k_compact(const int* __restrict__ src, const int* __restrict__ dst,
                          const int* __restrict__ nidx, int* __restrict__ pvs,
                          int* __restrict__ pvd, int* __restrict__ pcount, int E) {
    int e = blockIdx.x * blockDim.x + threadIdx.x;
    if (e >= E) return;
    int vs = nidx[src[e]], vd = nidx[dst[e]];
    if (vs >= 0 && vd >= 0) {
        int slot = atomicAdd(pcount, 1);
        if (slot < PCAP) { pvs[slot] = vs; pvd[slot] = vd; }
    }
}

// ---------------- entire pooled pipeline in one block ----------------
__global__ void k_pooled(const int* __restrict__ pvs, const int* __restrict__ pvd,
                         const int* __restrict__ pcount, const int* __restrict__ sel,
                         const float* __restrict__ xc, const float* __restrict__ score,
                         const float* __restrict__ x, const float* __restrict__ Wp,
                         const float* __restrict__ bp,
                         float* degp, float* b0, float* b1, float* b2,
                         float* pacc, float* selpos) {
    const int tid = threadIdx.x, NT = blockDim.x;
    const int pE = min(*pcount, PCAP);
    float* bufs[3] = {b0, b1, b2};
    for (int j = tid; j < KSEL; j += NT) AS(&degp[j], 0.0f);
    __syncthreads();
    for (int e = tid; e < pE; e += NT) atomicAdd(&degp[pvs[e]], 1.0f);
    __syncthreads();
    for (int j = tid; j < KSEL; j += NT) {
        float v = AL(&degp[j]);
        AS(&degp[j], v > 0.f ? rsqrtf(v) : 0.f);
    }
    for (int j = tid; j < KSEL; j += NT) {
        int i = sel[j];
        float s = score[i];
        float a = xc[2 * i] * s, b = xc[2 * i + 1] * s;
        AS(&b0[2 * j], a); AS(&b0[2 * j + 1], b);
        pacc[2 * j]     = bp[0] + a * Wp[0] + b * Wp[2];
        pacc[2 * j + 1] = bp[1] + a * Wp[1] + b * Wp[3];
        selpos[2 * j] = x[i * FIN + 14]; selpos[2 * j + 1] = x[i * FIN + 15];
    }
    __syncthreads();
    int c = 0;
    for (int k = 1; k < KHOP; ++k) {
        float* cur = bufs[c];
        float* nxt = bufs[(c + 1) % 3];
        float* prv = bufs[(c + 2) % 3];
        for (int j = tid; j < 2 * KSEL; j += NT) AS(&nxt[j], 0.0f);
        __syncthreads();
        for (int e = tid; e < pE; e += NT) {
            int vs = pvs[e], vd = pvd[e];
            float w = -AL(&degp[vs]) * AL(&degp[vd]);
            atomicAdd(&nxt[2 * vd],     w * AL(&cur[2 * vs]));
            atomicAdd(&nxt[2 * vd + 1], w * AL(&cur[2 * vs + 1]));
        }
        __syncthreads();
        for (int j = tid; j < KSEL; j += NT) {
            float a = AL(&nxt[2 * j]), b = AL(&nxt[2 * j + 1]);
            if (k >= 2) {
                a = 2.f * a - AL(&prv[2 * j]); b = 2.f * b - AL(&prv[2 * j + 1]);
                AS(&nxt[2 * j], a); AS(&nxt[2 * j + 1], b);
            }
            pacc[2 * j]     += a * Wp[k * 4 + 0] + b * Wp[k * 4 + 2];
            pacc[2 * j + 1] += a * Wp[k * 4 + 1] + b * Wp[k * 4 + 3];
        }
        __syncthreads();
        c = (c + 1) % 3;
    }
}

// ---------------- nearest pooled node (2D argmin) ----------------
__global__ void k_nearest(const float* __restrict__ x, const float* __restrict__ selpos,
                          int* __restrict__ nearest, int n, int k) {
    __shared__ float sp[KSEL * 2];
    for (int j = threadIdx.x; j < k * 2; j += blockDim.x) sp[j] = selpos[j];
    __syncthreads();
    int i = blockIdx.x * blockDim.x + threadIdx.x;
    if (i >= n) return;
    float px = x[i * FIN + 14], py = x[i * FIN + 15];
    float best = 3.4e38f; int bj = 0;
    for (int j = 0; j < k; ++j) {
        float dx = px - sp[j * 2], dy = py - sp[j * 2 + 1];
        float d = dx * dx + dy * dy;
        if (d < best) { best = d; bj = j; }
    }
    nearest[i] = bj;
}

// ---------------- final linear (74 -> 10) ----------------
__global__ void k_final(const float* __restrict__ x1, const float* __restrict__ x2,
                        const float* __restrict__ xp2, const int* __restrict__ nearest,
                        const float* __restrict__ W3, const float* __restrict__ b3,
                        float* __restrict__ o, int n) {
    __shared__ float sW[740], sb[10];
    for (int i = threadIdx.x; i < 740; i += blockDim.x) sW[i] = W3[i];
    if (threadIdx.x < 10) sb[threadIdx.x] = b3[threadIdx.x];
    __syncthreads();
    int t = blockIdx.x * blockDim.x + threadIdx.x;
    if (t >= n * 10) return;
    int i = t / 10, c = t - 10 * (t / 10);
    float s = sb[c];
    const float* r1 = &x1[i * H1];
#pragma unroll
    for (int f = 0; f < H1; ++f) s = fmaf(r1[f], sW[f * 10 + c], s);
    const float* r2 = &x2[i * H2];
#pragma unroll
    for (int f = 0; f < H2; ++f) s = fmaf(r2[f], sW[(H1 + f) * 10 + c], s);
    int m = nearest[i];
    s = fmaf(xp2[m * 2],     sW[720 + c], s);
    s = fmaf(xp2[m * 2 + 1], sW[730 + c], s);
    o[t] = s;
}

// =====================================================================
extern "C" void kernel_launch(void* const* d_in, const int* in_sizes, int n_in,
                              void* d_out, int out_size, void* d_ws, size_t ws_size,
                              hipStream_t stream) {
    const float* x   = (const float*)d_in[0];
    const int*   ei  = (const int*)d_in[1];
    const int*   src = ei;
    const int*   dst = ei + NE;
    const float* W1  = (const float*)d_in[2];
    const float* b1  = (const float*)d_in[3];
    const float* W2  = (const float*)d_in[4];
    const float* b2  = (const float*)d_in[5];
    const float* g1  = (const float*)d_in[6];
    const float* be1 = (const float*)d_in[7];
    const float* g2  = (const float*)d_in[8];
    const float* be2 = (const float*)d_in[9];
    const float* Wc  = (const float*)d_in[10];
    const float* bc  = (const float*)d_in[11];
    const float* pw  = (const float*)d_in[12];
    const float* Wp  = (const float*)d_in[13];
    const float* bp  = (const float*)d_in[14];
    const float* W3  = (const float*)d_in[15];
    const float* b3  = (const float*)d_in[16];
    float* out = (float*)d_out;

    // ---- workspace layout ----
    char* w = (char*)d_ws;
    auto alloc = [&](size_t bytes) -> void* {
        void* p = (void*)w;
        w += (bytes + 255) & ~(size_t)255;
        return p;
    };
    int*   cnt_src  = (int*)alloc(NN * 4);
    int*   cnt_dst  = (int*)alloc(NN * 4);
    float* dinv     = (float*)alloc(NN * 4);
    int*   rowstart = (int*)alloc((NN + 1) * 4);
    int*   cursor   = (int*)alloc(NN * 4);
    int2*  csr      = (int2*)alloc((size_t)NE * 8);
    float* B1    = (float*)alloc((size_t)NN * H1 * 4);
    float* B2    = (float*)alloc((size_t)NN * H1 * 4);
    float* B3    = (float*)alloc((size_t)NN * H1 * 4);
    float* acc   = (float*)alloc((size_t)NN * H1 * 4);
    float* x1    = (float*)alloc((size_t)NN * H1 * 4);
    float* x2    = (float*)alloc((size_t)NN * H2 * 4);
    float* xc    = (float*)alloc((size_t)NN * 2 * 4);
    float* score = (float*)alloc(NN * 4);
    float* stats = (float*)alloc(2 * H1 * 4);
    unsigned* key   = (unsigned*)alloc(NN * 4);
    int* nidx       = (int*)alloc(NN * 4);
    int* sel        = (int*)alloc(KSEL * 4);
    int* nearest    = (int*)alloc(NN * 4);
    unsigned* Tptr  = (unsigned*)alloc(4);
    int* Rptr       = (int*)alloc(4);
    int* pvs        = (int*)alloc(PCAP * 4);
    int* pvd        = (int*)alloc(PCAP * 4);
    int* pcount     = (int*)alloc(4);
    float* degp     = (float*)alloc(KSEL * 4);
    float* pb0      = (float*)alloc(KSEL * 2 * 4);
    float* pb1      = (float*)alloc(KSEL * 2 * 4);
    float* pb2      = (float*)alloc(KSEL * 2 * 4);
    float* pacc     = (float*)alloc(KSEL * 2 * 4);
    float* selpos   = (float*)alloc(KSEL * 2 * 4);

    const int NBK = (NN + 63) / 64;

    // ---- degree + CSR build ----
    hipMemsetAsync(cnt_src, 0, NN * 4, stream);
    hipMemsetAsync(cnt_dst, 0, NN * 4, stream);
    hipMemsetAsync(cursor, 0, NN * 4, stream);
    hipMemsetAsync(pcount, 0, 4, stream);
    k_count2<<<nb(NE), TPB, 0, stream>>>(src, dst, cnt_src, cnt_dst, NE);
    k_dinv2<<<nb(NN), TPB, 0, stream>>>(cnt_src, dinv, NN);
    k_scan<<<1, 1024, 0, stream>>>(cnt_dst, rowstart, NN);
    k_fill<<<nb(NE), TPB, 0, stream>>>(src, dst, dinv, rowstart, cursor, csr, NE);

    // ---- conv1: K=8, 16 -> 36 ----
    {
        k_gemm_init<FIN, H1><<<nb((long long)NN * H1), TPB, 0, stream>>>(x, W1, b1, acc, NN);
        float* rot[3] = {B1, B2, B3};
        k_prop_gemm<FIN, H1, 64><<<NBK, 64 * (FIN / 4), 0, stream>>>(
            rowstart, csr, x, nullptr, W1 + FIN * H1, B1, acc, NN, 1);
        const float* t_prev = x; const float* t_cur = B1;
        for (int kk = 2; kk < KHOP; ++kk) {
            float* o = rot[(kk - 1) % 3];
            k_prop_gemm<FIN, H1, 64><<<NBK, 64 * (FIN / 4), 0, stream>>>(
                rowstart, csr, t_cur, t_prev, W1 + kk * FIN * H1, o, acc, NN, 0);
            t_prev = t_cur; t_cur = o;
        }
        hipMemsetAsync(stats, 0, 2 * H1 * 4, stream);
        k_colstats<H1><<<120, TPB, 0, stream>>>(acc, stats, NN);
        k_bn<H1><<<nb((long long)NN * H1), TPB, 0, stream>>>(acc, stats, g1, be1, x1, NN);
    }

    // ---- conv2: K=8, 36 -> 36 ----
    {
        k_gemm_init<H1, H2><<<nb((long long)NN * H2), TPB, 0, stream>>>(x1, W2, b2, acc, NN);
        float* rot[3] = {B1, B2, B3};
        k_prop_gemm<H1, H2, 64><<<NBK, 64 * (H1 / 4), 0, stream>>>(
            rowstart, csr, x1, nullptr, W2 + H1 * H2, B1, acc, NN, 1);
        const float* t_prev = x1; const float* t_cur = B1;
        for (int kk = 2; kk < KHOP; ++kk) {
            float* o = rot[(kk - 1) % 3];
            k_prop_gemm<H1, H2, 64><<<NBK, 64 * (H1 / 4), 0, stream>>>(
                rowstart, csr, t_cur, t_prev, W2 + kk * H1 * H2, o, acc, NN, 0);
            t_prev = t_cur; t_cur = o;
        }
        hipMemsetAsync(stats, 0, 2 * H2 * 4, stream);
        k_colstats<H2><<<120, TPB, 0, stream>>>(acc, stats, NN);
        k_bn<H2><<<nb((long long)NN * H2), TPB, 0, stream>>>(acc, stats, g2, be2, x2, NN);
    }

    // ---- xc, score, key ----
    k_xc_score<<<nb(NN), TPB, 0, stream>>>(x1, Wc, bc, pw, xc, score, key, NN);

    // ---- top-k selection ----
    k_kth<<<1, 1024, 0, stream>>>(key, NN, KSEL, Tptr, Rptr);
    k_select<<<1, 1024, 0, stream>>>(key, Tptr, Rptr, nidx, sel, NN);

    // ---- pooled graph: compact edges, then single-block pipeline ----
    k_compact<<<nb(NE), TPB, 0, stream>>>(src, dst, nidx, pvs, pvd, pcount, NE);
    k_pooled<<<1, 1024, 0, stream>>>(pvs, pvd, pcount, sel, xc, score, x, Wp, bp,
                                     degp, pb0, pb1, pb2, pacc, selpos);

    // ---- nearest pooled node, final linear ----
    k_nearest<<<nb(NN), TPB, 0, stream>>>(x, selpos, nearest, NN, KSEL);
    k_final<<<nb((long long)NN * 10), TPB, 0, stream>>>(x1, x2, pacc, nearest, W3, b3, out, NN);
}

// Round 3
// 1024.076 us; speedup vs baseline: 2.1685x; 1.4136x over previous
//
#include <hip/hip_runtime.h>
#include <cstdint>

constexpr int NN   = 30000;
constexpr int NE   = 960000;
constexpr int FIN  = 16;
constexpr int H1   = 36;
constexpr int H2   = 36;
constexpr int KHOP = 8;
constexpr int KSEL = 3000;   // ceil(0.1 * 30000)
constexpr int PCAP = 32768;  // pooled-edge capacity (expected ~9600)
constexpr float EPSV = 1e-5f;

#define TPB 256

static inline int nb(long long t) { return (int)((t + TPB - 1) / TPB); }

// ---------------- degree counting (src for norm, dst for CSR) ----------------
__global__ void k_count2(const int* __restrict__ src, const int* __restrict__ dst,
                         int* __restrict__ cnt_src, int* __restrict__ cnt_dst, int E) {
    int e = blockIdx.x * blockDim.x + threadIdx.x;
    if (e >= E) return;
    atomicAdd(&cnt_src[src[e]], 1);
    atomicAdd(&cnt_dst[dst[e]], 1);
}

__global__ void k_dinv2(const int* __restrict__ cnt, float* __restrict__ dinv, int n) {
    int i = blockIdx.x * blockDim.x + threadIdx.x;
    if (i < n) { int v = cnt[i]; dinv[i] = v > 0 ? rsqrtf((float)v) : 0.0f; }
}

// ---------------- block scan helper (blockDim must be 1024) ----------------
__device__ __forceinline__ int block_scan_excl_1024(int val, int& total) {
    __shared__ int wsum[16];
    int tid = threadIdx.x, lane = tid & 63, wv = tid >> 6;
    int v = val;
#pragma unroll
    for (int off = 1; off < 64; off <<= 1) {
        int t = __shfl_up(v, off, 64);
        if (lane >= off) v += t;
    }
    __syncthreads();
    if (lane == 63) wsum[wv] = v;
    __syncthreads();
    if (tid < 16) {
        int w = wsum[tid];
#pragma unroll
        for (int off = 1; off < 16; off <<= 1) {
            int t = __shfl_up(w, off, 64);
            if (tid >= off) w += t;
        }
        wsum[tid] = w;
    }
    __syncthreads();
    int base = (wv > 0) ? wsum[wv - 1] : 0;
    total = wsum[15];
    return base + v - val;
}

__global__ void k_scan(const int* __restrict__ cnt, int* __restrict__ rowstart, int n) {
    __shared__ int run;
    if (threadIdx.x == 0) run = 0;
    __syncthreads();
    for (int base = 0; base < n; base += 1024) {
        int i = base + threadIdx.x;
        int v = (i < n) ? cnt[i] : 0;
        int tot; int ex = block_scan_excl_1024(v, tot);
        int r = run;
        if (i < n) rowstart[i] = r + ex;
        __syncthreads();
        if (threadIdx.x == 0) run += tot;
        __syncthreads();
    }
    if (threadIdx.x == 0) rowstart[n] = run;
}

// ---------------- CSR fill: (src, norm-weight) pairs grouped by dst ----------------
__global__ void k_fill(const int* __restrict__ src, const int* __restrict__ dst,
                       const float* __restrict__ dinv, const int* __restrict__ rowstart,
                       int* __restrict__ cursor, int2* __restrict__ csr, int E) {
    int e = blockIdx.x * blockDim.x + threadIdx.x;
    if (e >= E) return;
    int s = src[e], d = dst[e];
    int pos = atomicAdd(&cursor[d], 1);
    float w = -dinv[s] * dinv[d];
    csr[rowstart[d] + pos] = make_int2(s, __float_as_int(w));
}

// ---------------- acc = b + in @ W[0] ----------------
template<int F, int O>
__global__ void k_gemm_init(const float* __restrict__ in, const float* __restrict__ W,
                            const float* __restrict__ b, float* __restrict__ acc, int n) {
    __shared__ float sW[F * O];
    for (int i = threadIdx.x; i < F * O; i += blockDim.x) sW[i] = W[i];
    __syncthreads();
    int t = blockIdx.x * blockDim.x + threadIdx.x;
    if (t >= n * O) return;
    int node = t / O, o = t - node * O;
    const float* r = &in[node * F];
    float s = b[o];
#pragma unroll
    for (int f = 0; f < F; ++f) s = fmaf(r[f], sW[f * O + o], s);
    acc[t] = s;
}

// ---------------- fused: t_k = (2?)*(-Ahat h) - t0 ; tout=t_k ; acc += t_k @ W ----------------
template<int F, int O, int BN>
__global__ __launch_bounds__(BN * F / 4)
void k_prop_gemm(const int* __restrict__ rowstart, const int2* __restrict__ csr,
                 const float* __restrict__ h, const float* __restrict__ t0,
                 const float* __restrict__ W, float* __restrict__ tout,
                 float* __restrict__ acc, int n, int first) {
    constexpr int QF = F / 4;
    constexpr int NT = BN * QF;
    __shared__ float sT[BN * F];
    __shared__ float sW[F * O];
    const int tid = threadIdx.x;
    for (int i = tid; i < F * O; i += NT) sW[i] = W[i];
    const int nl = tid / QF, q = tid - nl * QF;
    const int node = blockIdx.x * BN + nl;
    if (node < n) {
        const float4* __restrict__ h4 = (const float4*)h;
        float4 p = {0.f, 0.f, 0.f, 0.f};
        int e0 = rowstart[node], e1 = rowstart[node + 1];
        for (int e = e0; e < e1; ++e) {
            int2 ew = csr[e];
            float w = __int_as_float(ew.y);
            float4 hv = h4[ew.x * QF + q];
            p.x = fmaf(w, hv.x, p.x); p.y = fmaf(w, hv.y, p.y);
            p.z = fmaf(w, hv.z, p.z); p.w = fmaf(w, hv.w, p.w);
        }
        if (!first) {
            float4 tv = ((const float4*)t0)[node * QF + q];
            p.x = 2.f * p.x - tv.x; p.y = 2.f * p.y - tv.y;
            p.z = 2.f * p.z - tv.z; p.w = 2.f * p.w - tv.w;
        }
        ((float4*)tout)[node * QF + q] = p;
        sT[nl * F + 4 * q + 0] = p.x; sT[nl * F + 4 * q + 1] = p.y;
        sT[nl * F + 4 * q + 2] = p.z; sT[nl * F + 4 * q + 3] = p.w;
    }
    __syncthreads();
    for (int idx = tid; idx < BN * O; idx += NT) {
        int nl2 = idx / O, o = idx - nl2 * O;
        int gn = blockIdx.x * BN + nl2;
        if (gn >= n) break;
        float s = 0.f;
#pragma unroll
        for (int f = 0; f < F; ++f) s = fmaf(sT[nl2 * F + f], sW[f * O + o], s);
        acc[gn * O + o] += s;
    }
}

// ---------------- relu + batchnorm ----------------
template<int C>
__global__ void k_colstats(const float* __restrict__ a, float* __restrict__ stats, int n) {
    __shared__ float s1[C], s2[C];
    for (int i = threadIdx.x; i < C; i += blockDim.x) { s1[i] = 0.f; s2[i] = 0.f; }
    __syncthreads();
    int total = n * C, stride = gridDim.x * blockDim.x;
    for (int t = blockIdx.x * blockDim.x + threadIdx.x; t < total; t += stride) {
        float v = fmaxf(a[t], 0.f); int c = t % C;
        atomicAdd(&s1[c], v); atomicAdd(&s2[c], v * v);
    }
    __syncthreads();
    for (int i = threadIdx.x; i < C; i += blockDim.x) {
        atomicAdd(&stats[i], s1[i]); atomicAdd(&stats[C + i], s2[i]);
    }
}

template<int C>
__global__ void k_bn(const float* __restrict__ a, const float* __restrict__ stats,
                     const float* __restrict__ g, const float* __restrict__ be,
                     float* __restrict__ o, int n) {
    int t = blockIdx.x * blockDim.x + threadIdx.x;
    if (t >= n * C) return;
    int c = t % C;
    float mu = stats[c] / n;
    float var = stats[C + c] / n - mu * mu;
    float v = fmaxf(a[t], 0.f);
    o[t] = (v - mu) * rsqrtf(var + EPSV) * g[c] + be[c];
}

// ---------------- xc, score, sortable key ----------------
__global__ void k_xc_score(const float* __restrict__ x1, const float* __restrict__ Wc,
                           const float* __restrict__ bc, const float* __restrict__ pw,
                           float* __restrict__ xc, float* __restrict__ score,
                           unsigned* __restrict__ key, int n) {
    int i = blockIdx.x * blockDim.x + threadIdx.x;
    if (i >= n) return;
    const float* r = &x1[i * H1];
    float a = bc[0], b = bc[1];
#pragma unroll
    for (int f = 0; f < H1; ++f) { float v = r[f]; a = fmaf(v, Wc[f * 2], a); b = fmaf(v, Wc[f * 2 + 1], b); }
    xc[i * 2] = a; xc[i * 2 + 1] = b;
    float w0 = pw[0], w1 = pw[1];
    float s = tanhf((a * w0 + b * w1) / sqrtf(w0 * w0 + w1 * w1));
    score[i] = s;
    unsigned u = __float_as_uint(s);
    key[i] = (u & 0x80000000u) ? ~u : (u | 0x80000000u);
}

// ---------------- radix select: T = k-th largest key, r = #(==T) to take ----------------
__global__ void k_kth(const unsigned* __restrict__ key, int n, int k,
                      unsigned* __restrict__ outT, int* __restrict__ outR) {
    __shared__ int hist[256];
    __shared__ unsigned sprefix;
    __shared__ int skrem;
    int tid = threadIdx.x;
    if (tid == 0) { sprefix = 0u; skrem = k; }
    for (int pass = 3; pass >= 0; --pass) {
        __syncthreads();
        for (int i = tid; i < 256; i += blockDim.x) hist[i] = 0;
        __syncthreads();
        unsigned pref = sprefix;
        int shift = (pass + 1) * 8;
        for (int i = tid; i < n; i += blockDim.x) {
            unsigned kk = key[i];
            bool match = ((unsigned long long)kk >> shift) == ((unsigned long long)pref >> shift);
            if (match) atomicAdd(&hist[(kk >> (pass * 8)) & 0xFF], 1);
        }
        __syncthreads();
        if (tid == 0) {
            int krem = skrem;
            int cum = 0; int d = 0;
            for (int b = 255; b >= 0; --b) {
                if (cum + hist[b] >= krem) { d = b; break; }
                cum += hist[b];
            }
            sprefix |= ((unsigned)d) << (pass * 8);
            skrem = krem - cum;
        }
    }
    __syncthreads();
    if (tid == 0) { *outT = sprefix; *outR = skrem; }
}

__global__ void k_select(const unsigned* __restrict__ key, const unsigned* __restrict__ pT,
                         const int* __restrict__ pR, int* __restrict__ nidx,
                         int* __restrict__ sel, int n) {
    unsigned T = *pT; int r = *pR;
    __shared__ int run_sel, run_eq;
    if (threadIdx.x == 0) { run_sel = 0; run_eq = 0; }
    __syncthreads();
    for (int base = 0; base < n; base += 1024) {
        int i = base + threadIdx.x;
        unsigned kk = (i < n) ? key[i] : 0u;
        int eq = (i < n && kk == T) ? 1 : 0;
        int gt = (i < n && kk > T) ? 1 : 0;
        int eq_tot; int eq_ex = block_scan_excl_1024(eq, eq_tot);
        int re = run_eq;
        int sf = gt | (eq & (((re + eq_ex) < r) ? 1 : 0));
        int s_tot; int s_ex = block_scan_excl_1024(sf, s_tot);
        int rs = run_sel;
        if (i < n) {
            if (sf) { int slot = rs + s_ex; nidx[i] = slot; sel[slot] = i; }
            else nidx[i] = -1;
        }
        __syncthreads();
        if (threadIdx.x == 0) { run_sel = rs + s_tot; run_eq = re + eq_tot; }
        __syncthreads();
    }
}

// ---------------- compact pooled edges ----------------
__global__ void k_compact(const int* __restrict__ src, const int* __restrict__ dst,
                          const int* __restrict__ nidx, int* __restrict__ pvs,
                          int* __restrict__ pvd, int* __restrict__ pcount, int E) {
    int e = blockIdx.x * blockDim.x + threadIdx.x;
    if (e >= E) return;
    int vs = nidx[src[e]], vd = nidx[dst[e]];
    if (vs >= 0 && vd >= 0) {
        int slot = atomicAdd(pcount, 1);
        if (slot < PCAP) { pvs[slot] = vs; pvd[slot] = vd; }
    }
}

// ---------------- entire pooled pipeline in one block, LDS-resident ----------------
__global__ __launch_bounds__(1024)
void k_pooled2(const int* __restrict__ pvs, const int* __restrict__ pvd,
               const int* __restrict__ pcount, const int* __restrict__ sel,
               const float* __restrict__ xc, const float* __restrict__ score,
               const float* __restrict__ x, const float* __restrict__ Wp,
               const float* __restrict__ bp, int2* __restrict__ gcsr,
               float* __restrict__ pacc_out, float* __restrict__ selpos) {
    __shared__ float bufA[2 * KSEL];         // 24 KB (T buffers / build scratch)
    __shared__ float bufB[2 * KSEL];         // 24 KB
    __shared__ int   rowstart[KSEL + 1];     // 12 KB
    __shared__ int   s_run;
    const int tid = threadIdx.x, NT = 1024;
    const int pE = min(*pcount, PCAP);

    // --- build phase (overlays: cnt_src/cnt_dst in bufB, dinvp in bufA) ---
    int* cnt_src = (int*)bufB;
    int* cnt_dst = ((int*)bufB) + KSEL;
    float* dinvp = bufA;
    for (int j = tid; j < KSEL; j += NT) { cnt_src[j] = 0; cnt_dst[j] = 0; }
    __syncthreads();
    for (int e = tid; e < pE; e += NT) {
        atomicAdd(&cnt_src[pvs[e]], 1);
        atomicAdd(&cnt_dst[pvd[e]], 1);
    }
    __syncthreads();
    for (int j = tid; j < KSEL; j += NT) {
        int c = cnt_src[j];
        dinvp[j] = c > 0 ? rsqrtf((float)c) : 0.0f;
    }
    // scan cnt_dst -> rowstart
    if (tid == 0) s_run = 0;
    __syncthreads();
    for (int base = 0; base < KSEL; base += NT) {
        int i = base + tid;
        int v = (i < KSEL) ? cnt_dst[i] : 0;
        int tot; int ex = block_scan_excl_1024(v, tot);
        int r = s_run;
        if (i < KSEL) rowstart[i] = r + ex;
        __syncthreads();
        if (tid == 0) s_run += tot;
        __syncthreads();
    }
    if (tid == 0) rowstart[KSEL] = s_run;
    // cursor reuses cnt_dst
    for (int j = tid; j < KSEL; j += NT) cnt_dst[j] = 0;
    __syncthreads();
    for (int e = tid; e < pE; e += NT) {
        int vs = pvs[e], vd = pvd[e];
        int pos = atomicAdd(&cnt_dst[vd], 1);
        float w = -dinvp[vs] * dinvp[vd];
        gcsr[rowstart[vd] + pos] = make_int2(vs, __float_as_int(w));
    }
    __syncthreads();

    // --- init: T0 = xp1 into bufA; pacc in registers ---
    const float bp0 = bp[0], bp1 = bp[1];
    float accA[3], accB[3];
#pragma unroll
    for (int r = 0; r < 3; ++r) {
        int j = tid + r * NT;
        accA[r] = 0.f; accB[r] = 0.f;
        if (j < KSEL) {
            int i = sel[j];
            float s = score[i];
            float a = xc[2 * i] * s, b = xc[2 * i + 1] * s;
            bufA[2 * j] = a; bufA[2 * j + 1] = b;
            accA[r] = bp0 + a * Wp[0] + b * Wp[2];
            accB[r] = bp1 + a * Wp[1] + b * Wp[3];
            selpos[2 * j] = x[i * FIN + 14];
            selpos[2 * j + 1] = x[i * FIN + 15];
        }
    }
    __syncthreads();

    // --- 7 hops, ping-pong LDS buffers ---
    for (int k = 1; k < KHOP; ++k) {
        float* rb = (k & 1) ? bufA : bufB;
        float* wb = (k & 1) ? bufB : bufA;
        float w0 = Wp[k * 4 + 0], w1 = Wp[k * 4 + 1];
        float w2 = Wp[k * 4 + 2], w3 = Wp[k * 4 + 3];
#pragma unroll
        for (int r = 0; r < 3; ++r) {
            int j = tid + r * NT;
            if (j < KSEL) {
                float pa = 0.f, pb = 0.f;
                int e0 = rowstart[j], e1 = rowstart[j + 1];
                for (int e = e0; e < e1; ++e) {
                    int2 ew = gcsr[e];
                    float w = __int_as_float(ew.y);
                    pa = fmaf(w, rb[2 * ew.x], pa);
                    pb = fmaf(w, rb[2 * ew.x + 1], pb);
                }
                if (k >= 2) {
                    pa = 2.f * pa - wb[2 * j];
                    pb = 2.f * pb - wb[2 * j + 1];
                }
                wb[2 * j] = pa; wb[2 * j + 1] = pb;
                accA[r] = fmaf(pa, w0, fmaf(pb, w2, accA[r]));
                accB[r] = fmaf(pa, w1, fmaf(pb, w3, accB[r]));
            }
        }
        __syncthreads();
    }

    // --- write pacc ---
#pragma unroll
    for (int r = 0; r < 3; ++r) {
        int j = tid + r * NT;
        if (j < KSEL) {
            pacc_out[2 * j] = accA[r];
            pacc_out[2 * j + 1] = accB[r];
        }
    }
}

// ---------------- nearest pooled node (2D argmin) ----------------
__global__ void k_nearest(const float* __restrict__ x, const float* __restrict__ selpos,
                          int* __restrict__ nearest, int n, int k) {
    __shared__ float sp[KSEL * 2];
    for (int j = threadIdx.x; j < k * 2; j += blockDim.x) sp[j] = selpos[j];
    __syncthreads();
    int i = blockIdx.x * blockDim.x + threadIdx.x;
    if (i >= n) return;
    float px = x[i * FIN + 14], py = x[i * FIN + 15];
    float best = 3.4e38f; int bj = 0;
    for (int j = 0; j < k; ++j) {
        float dx = px - sp[j * 2], dy = py - sp[j * 2 + 1];
        float d = dx * dx + dy * dy;
        if (d < best) { best = d; bj = j; }
    }
    nearest[i] = bj;
}

// ---------------- final linear (74 -> 10) ----------------
__global__ void k_final(const float* __restrict__ x1, const float* __restrict__ x2,
                        const float* __restrict__ xp2, const int* __restrict__ nearest,
                        const float* __restrict__ W3, const float* __restrict__ b3,
                        float* __restrict__ o, int n) {
    __shared__ float sW[740], sb[10];
    for (int i = threadIdx.x; i < 740; i += blockDim.x) sW[i] = W3[i];
    if (threadIdx.x < 10) sb[threadIdx.x] = b3[threadIdx.x];
    __syncthreads();
    int t = blockIdx.x * blockDim.x + threadIdx.x;
    if (t >= n * 10) return;
    int i = t / 10, c = t - 10 * (t / 10);
    float s = sb[c];
    const float* r1 = &x1[i * H1];
#pragma unroll
    for (int f = 0; f < H1; ++f) s = fmaf(r1[f], sW[f * 10 + c], s);
    const float* r2 = &x2[i * H2];
#pragma unroll
    for (int f = 0; f < H2; ++f) s = fmaf(r2[f], sW[(H1 + f) * 10 + c], s);
    int m = nearest[i];
    s = fmaf(xp2[m * 2],     sW[720 + c], s);
    s = fmaf(xp2[m * 2 + 1], sW[730 + c], s);
    o[t] = s;
}

// =====================================================================
extern "C" void kernel_launch(void* const* d_in, const int* in_sizes, int n_in,
                              void* d_out, int out_size, void* d_ws, size_t ws_size,
                              hipStream_t stream) {
    const float* x   = (const float*)d_in[0];
    const int*   ei  = (const int*)d_in[1];
    const int*   src = ei;
    const int*   dst = ei + NE;
    const float* W1  = (const float*)d_in[2];
    const float* b1  = (const float*)d_in[3];
    const float* W2  = (const float*)d_in[4];
    const float* b2  = (const float*)d_in[5];
    const float* g1  = (const float*)d_in[6];
    const float* be1 = (const float*)d_in[7];
    const float* g2  = (const float*)d_in[8];
    const float* be2 = (const float*)d_in[9];
    const float* Wc  = (const float*)d_in[10];
    const float* bc  = (const float*)d_in[11];
    const float* pw  = (const float*)d_in[12];
    const float* Wp  = (const float*)d_in[13];
    const float* bp  = (const float*)d_in[14];
    const float* W3  = (const float*)d_in[15];
    const float* b3  = (const float*)d_in[16];
    float* out = (float*)d_out;

    // ---- workspace layout ----
    char* w = (char*)d_ws;
    auto alloc = [&](size_t bytes) -> void* {
        void* p = (void*)w;
        w += (bytes + 255) & ~(size_t)255;
        return p;
    };
    int*   cnt_src  = (int*)alloc(NN * 4);
    int*   cnt_dst  = (int*)alloc(NN * 4);
    float* dinv     = (float*)alloc(NN * 4);
    int*   rowstart = (int*)alloc((NN + 1) * 4);
    int*   cursor   = (int*)alloc(NN * 4);
    int2*  csr      = (int2*)alloc((size_t)NE * 8);
    float* B1    = (float*)alloc((size_t)NN * H1 * 4);
    float* B2    = (float*)alloc((size_t)NN * H1 * 4);
    float* B3    = (float*)alloc((size_t)NN * H1 * 4);
    float* acc   = (float*)alloc((size_t)NN * H1 * 4);
    float* x1    = (float*)alloc((size_t)NN * H1 * 4);
    float* x2    = (float*)alloc((size_t)NN * H2 * 4);
    float* xc    = (float*)alloc((size_t)NN * 2 * 4);
    float* score = (float*)alloc(NN * 4);
    float* stats = (float*)alloc(2 * H1 * 4);
    unsigned* key   = (unsigned*)alloc(NN * 4);
    int* nidx       = (int*)alloc(NN * 4);
    int* sel        = (int*)alloc(KSEL * 4);
    int* nearest    = (int*)alloc(NN * 4);
    unsigned* Tptr  = (unsigned*)alloc(4);
    int* Rptr       = (int*)alloc(4);
    int* pvs        = (int*)alloc(PCAP * 4);
    int* pvd        = (int*)alloc(PCAP * 4);
    int* pcount     = (int*)alloc(4);
    int2* gcsr      = (int2*)alloc((size_t)PCAP * 8);
    float* pacc     = (float*)alloc(KSEL * 2 * 4);
    float* selpos   = (float*)alloc(KSEL * 2 * 4);

    const int NBK = (NN + 63) / 64;

    // ---- degree + CSR build ----
    hipMemsetAsync(cnt_src, 0, NN * 4, stream);
    hipMemsetAsync(cnt_dst, 0, NN * 4, stream);
    hipMemsetAsync(cursor, 0, NN * 4, stream);
    hipMemsetAsync(pcount, 0, 4, stream);
    k_count2<<<nb(NE), TPB, 0, stream>>>(src, dst, cnt_src, cnt_dst, NE);
    k_dinv2<<<nb(NN), TPB, 0, stream>>>(cnt_src, dinv, NN);
    k_scan<<<1, 1024, 0, stream>>>(cnt_dst, rowstart, NN);
    k_fill<<<nb(NE), TPB, 0, stream>>>(src, dst, dinv, rowstart, cursor, csr, NE);

    // ---- conv1: K=8, 16 -> 36 ----
    {
        k_gemm_init<FIN, H1><<<nb((long long)NN * H1), TPB, 0, stream>>>(x, W1, b1, acc, NN);
        float* rot[3] = {B1, B2, B3};
        k_prop_gemm<FIN, H1, 64><<<NBK, 64 * (FIN / 4), 0, stream>>>(
            rowstart, csr, x, nullptr, W1 + FIN * H1, B1, acc, NN, 1);
        const float* t_prev = x; const float* t_cur = B1;
        for (int kk = 2; kk < KHOP; ++kk) {
            float* o = rot[(kk - 1) % 3];
            k_prop_gemm<FIN, H1, 64><<<NBK, 64 * (FIN / 4), 0, stream>>>(
                rowstart, csr, t_cur, t_prev, W1 + kk * FIN * H1, o, acc, NN, 0);
            t_prev = t_cur; t_cur = o;
        }
        hipMemsetAsync(stats, 0, 2 * H1 * 4, stream);
        k_colstats<H1><<<120, TPB, 0, stream>>>(acc, stats, NN);
        k_bn<H1><<<nb((long long)NN * H1), TPB, 0, stream>>>(acc, stats, g1, be1, x1, NN);
    }

    // ---- conv2: K=8, 36 -> 36 ----
    {
        k_gemm_init<H1, H2><<<nb((long long)NN * H2), TPB, 0, stream>>>(x1, W2, b2, acc, NN);
        float* rot[3] = {B1, B2, B3};
        k_prop_gemm<H1, H2, 64><<<NBK, 64 * (H1 / 4), 0, stream>>>(
            rowstart, csr, x1, nullptr, W2 + H1 * H2, B1, acc, NN, 1);
        const float* t_prev = x1; const float* t_cur = B1;
        for (int kk = 2; kk < KHOP; ++kk) {
            float* o = rot[(kk - 1) % 3];
            k_prop_gemm<H1, H2, 64><<<NBK, 64 * (H1 / 4), 0, stream>>>(
                rowstart, csr, t_cur, t_prev, W2 + kk * H1 * H2, o, acc, NN, 0);
            t_prev = t_cur; t_cur = o;
        }
        hipMemsetAsync(stats, 0, 2 * H2 * 4, stream);
        k_colstats<H2><<<120, TPB, 0, stream>>>(acc, stats, NN);
        k_bn<H2><<<nb((long long)NN * H2), TPB, 0, stream>>>(acc, stats, g2, be2, x2, NN);
    }

    // ---- xc, score, key ----
    k_xc_score<<<nb(NN), TPB, 0, stream>>>(x1, Wc, bc, pw, xc, score, key, NN);

    // ---- top-k selection ----
    k_kth<<<1, 1024, 0, stream>>>(key, NN, KSEL, Tptr, Rptr);
    k_select<<<1, 1024, 0, stream>>>(key, Tptr, Rptr, nidx, sel, NN);

    // ---- pooled graph: compact edges, then single-block LDS pipeline ----
    k_compact<<<nb(NE), TPB, 0, stream>>>(src, dst, nidx, pvs, pvd, pcount, NE);
    k_pooled2<<<1, 1024, 0, stream>>>(pvs, pvd, pcount, sel, xc, score, x, Wp, bp,
                                      gcsr, pacc, selpos);

    // ---- nearest pooled node, final linear ----
    k_nearest<<<nb(NN), TPB, 0, stream>>>(x, selpos, nearest, NN, KSEL);
    k_final<<<nb((long long)NN * 10), TPB, 0, stream>>>(x1, x2, pacc, nearest, W3, b3, out, NN);
}

// Round 4
// 857.082 us; speedup vs baseline: 2.5911x; 1.1948x over previous
//
#include <hip/hip_runtime.h>
#include <cstdint>

constexpr int NN   = 30000;
constexpr int NE   = 960000;
constexpr int FIN  = 16;
constexpr int H1   = 36;
constexpr int H2   = 36;
constexpr int KHOP = 8;
constexpr int KSEL = 3000;   // ceil(0.1 * 30000)
constexpr int PCAP = 32768;  // pooled-edge capacity (expected ~9600)
constexpr int NCHUNK = 12;   // candidate chunks for nearest (3000/12 = 250)
constexpr int CHUNK = KSEL / NCHUNK;
constexpr float EPSV = 1e-5f;

#define TPB 256

static inline int nb(long long t) { return (int)((t + TPB - 1) / TPB); }

// ---------------- degree counting (src for norm, dst for CSR) ----------------
__global__ void k_count2(const int* __restrict__ src, const int* __restrict__ dst,
                         int* __restrict__ cnt_src, int* __restrict__ cnt_dst, int E) {
    int e = blockIdx.x * blockDim.x + threadIdx.x;
    if (e >= E) return;
    atomicAdd(&cnt_src[src[e]], 1);
    atomicAdd(&cnt_dst[dst[e]], 1);
}

__global__ void k_dinv2(const int* __restrict__ cnt, float* __restrict__ dinv, int n) {
    int i = blockIdx.x * blockDim.x + threadIdx.x;
    if (i < n) { int v = cnt[i]; dinv[i] = v > 0 ? rsqrtf((float)v) : 0.0f; }
}

// ---------------- block scan helper (blockDim must be 1024) ----------------
__device__ __forceinline__ int block_scan_excl_1024(int val, int& total) {
    __shared__ int wsum[16];
    int tid = threadIdx.x, lane = tid & 63, wv = tid >> 6;
    int v = val;
#pragma unroll
    for (int off = 1; off < 64; off <<= 1) {
        int t = __shfl_up(v, off, 64);
        if (lane >= off) v += t;
    }
    __syncthreads();
    if (lane == 63) wsum[wv] = v;
    __syncthreads();
    if (tid < 16) {
        int w = wsum[tid];
#pragma unroll
        for (int off = 1; off < 16; off <<= 1) {
            int t = __shfl_up(w, off, 64);
            if (tid >= off) w += t;
        }
        wsum[tid] = w;
    }
    __syncthreads();
    int base = (wv > 0) ? wsum[wv - 1] : 0;
    total = wsum[15];
    return base + v - val;
}

__global__ void k_scan(const int* __restrict__ cnt, int* __restrict__ rowstart, int n) {
    __shared__ int run;
    if (threadIdx.x == 0) run = 0;
    __syncthreads();
    for (int base = 0; base < n; base += 1024) {
        int i = base + threadIdx.x;
        int v = (i < n) ? cnt[i] : 0;
        int tot; int ex = block_scan_excl_1024(v, tot);
        int r = run;
        if (i < n) rowstart[i] = r + ex;
        __syncthreads();
        if (threadIdx.x == 0) run += tot;
        __syncthreads();
    }
    if (threadIdx.x == 0) rowstart[n] = run;
}

// ---------------- CSR fill: (src, norm-weight) pairs grouped by dst ----------------
__global__ void k_fill(const int* __restrict__ src, const int* __restrict__ dst,
                       const float* __restrict__ dinv, const int* __restrict__ rowstart,
                       int* __restrict__ cursor, int2* __restrict__ csr, int E) {
    int e = blockIdx.x * blockDim.x + threadIdx.x;
    if (e >= E) return;
    int s = src[e], d = dst[e];
    int pos = atomicAdd(&cursor[d], 1);
    float w = -dinv[s] * dinv[d];
    csr[rowstart[d] + pos] = make_int2(s, __float_as_int(w));
}

// ---------------- acc = b + in @ W[0] ----------------
template<int F, int O>
__global__ void k_gemm_init(const float* __restrict__ in, const float* __restrict__ W,
                            const float* __restrict__ b, float* __restrict__ acc, int n) {
    __shared__ float sW[F * O];
    for (int i = threadIdx.x; i < F * O; i += blockDim.x) sW[i] = W[i];
    __syncthreads();
    int t = blockIdx.x * blockDim.x + threadIdx.x;
    if (t >= n * O) return;
    int node = t / O, o = t - node * O;
    const float* r = &in[node * F];
    float s = b[o];
#pragma unroll
    for (int f = 0; f < F; ++f) s = fmaf(r[f], sW[f * O + o], s);
    acc[t] = s;
}

// ---------------- fused: t_k = (2?)*(-Ahat h) - t0 ; tout=t_k ; acc += t_k @ W ----------------
template<int F, int O, int BN>
__global__ __launch_bounds__(BN * F / 4)
void k_prop_gemm(const int* __restrict__ rowstart, const int2* __restrict__ csr,
                 const float* __restrict__ h, const float* __restrict__ t0,
                 const float* __restrict__ W, float* __restrict__ tout,
                 float* __restrict__ acc, int n, int first) {
    constexpr int QF = F / 4;
    constexpr int NT = BN * QF;
    __shared__ float sT[BN * F];
    __shared__ float sW[F * O];
    const int tid = threadIdx.x;
    for (int i = tid; i < F * O; i += NT) sW[i] = W[i];
    const int nl = tid / QF, q = tid - nl * QF;
    const int node = blockIdx.x * BN + nl;
    if (node < n) {
        const float4* __restrict__ h4 = (const float4*)h;
        float4 p = {0.f, 0.f, 0.f, 0.f};
        int e0 = rowstart[node], e1 = rowstart[node + 1];
        int e = e0;
        for (; e + 1 < e1; e += 2) {
            int2 ea = csr[e];
            int2 eb = csr[e + 1];
            float4 ha = h4[ea.x * QF + q];
            float4 hb = h4[eb.x * QF + q];
            float wa = __int_as_float(ea.y), wb = __int_as_float(eb.y);
            p.x = fmaf(wa, ha.x, p.x); p.y = fmaf(wa, ha.y, p.y);
            p.z = fmaf(wa, ha.z, p.z); p.w = fmaf(wa, ha.w, p.w);
            p.x = fmaf(wb, hb.x, p.x); p.y = fmaf(wb, hb.y, p.y);
            p.z = fmaf(wb, hb.z, p.z); p.w = fmaf(wb, hb.w, p.w);
        }
        if (e < e1) {
            int2 ew = csr[e];
            float w = __int_as_float(ew.y);
            float4 hv = h4[ew.x * QF + q];
            p.x = fmaf(w, hv.x, p.x); p.y = fmaf(w, hv.y, p.y);
            p.z = fmaf(w, hv.z, p.z); p.w = fmaf(w, hv.w, p.w);
        }
        if (!first) {
            float4 tv = ((const float4*)t0)[node * QF + q];
            p.x = 2.f * p.x - tv.x; p.y = 2.f * p.y - tv.y;
            p.z = 2.f * p.z - tv.z; p.w = 2.f * p.w - tv.w;
        }
        ((float4*)tout)[node * QF + q] = p;
        sT[nl * F + 4 * q + 0] = p.x; sT[nl * F + 4 * q + 1] = p.y;
        sT[nl * F + 4 * q + 2] = p.z; sT[nl * F + 4 * q + 3] = p.w;
    }
    __syncthreads();
    for (int idx = tid; idx < BN * O; idx += NT) {
        int nl2 = idx / O, o = idx - nl2 * O;
        int gn = blockIdx.x * BN + nl2;
        if (gn >= n) break;
        float s = 0.f;
#pragma unroll
        for (int f = 0; f < F; ++f) s = fmaf(sT[nl2 * F + f], sW[f * O + o], s);
        acc[gn * O + o] += s;
    }
}

// ---------------- relu + batchnorm ----------------
template<int C>
__global__ void k_colstats(const float* __restrict__ a, float* __restrict__ stats, int n) {
    __shared__ float s1[C], s2[C];
    for (int i = threadIdx.x; i < C; i += blockDim.x) { s1[i] = 0.f; s2[i] = 0.f; }
    __syncthreads();
    int total = n * C, stride = gridDim.x * blockDim.x;
    for (int t = blockIdx.x * blockDim.x + threadIdx.x; t < total; t += stride) {
        float v = fmaxf(a[t], 0.f); int c = t % C;
        atomicAdd(&s1[c], v); atomicAdd(&s2[c], v * v);
    }
    __syncthreads();
    for (int i = threadIdx.x; i < C; i += blockDim.x) {
        atomicAdd(&stats[i], s1[i]); atomicAdd(&stats[C + i], s2[i]);
    }
}

template<int C>
__global__ void k_bn(const float* __restrict__ a, const float* __restrict__ stats,
                     const float* __restrict__ g, const float* __restrict__ be,
                     float* __restrict__ o, int n) {
    int t = blockIdx.x * blockDim.x + threadIdx.x;
    if (t >= n * C) return;
    int c = t % C;
    float mu = stats[c] / n;
    float var = stats[C + c] / n - mu * mu;
    float v = fmaxf(a[t], 0.f);
    o[t] = (v - mu) * rsqrtf(var + EPSV) * g[c] + be[c];
}

// ---------------- xc, score, sortable key ----------------
__global__ void k_xc_score(const float* __restrict__ x1, const float* __restrict__ Wc,
                           const float* __restrict__ bc, const float* __restrict__ pw,
                           float* __restrict__ xc, float* __restrict__ score,
                           unsigned* __restrict__ key, int n) {
    int i = blockIdx.x * blockDim.x + threadIdx.x;
    if (i >= n) return;
    const float* r = &x1[i * H1];
    float a = bc[0], b = bc[1];
#pragma unroll
    for (int f = 0; f < H1; ++f) { float v = r[f]; a = fmaf(v, Wc[f * 2], a); b = fmaf(v, Wc[f * 2 + 1], b); }
    xc[i * 2] = a; xc[i * 2 + 1] = b;
    float w0 = pw[0], w1 = pw[1];
    float s = tanhf((a * w0 + b * w1) / sqrtf(w0 * w0 + w1 * w1));
    score[i] = s;
    unsigned u = __float_as_uint(s);
    key[i] = (u & 0x80000000u) ? ~u : (u | 0x80000000u);
}

// ---------------- radix select: T = k-th largest key, r = #(==T) to take ----------------
__global__ void k_kth(const unsigned* __restrict__ key, int n, int k,
                      unsigned* __restrict__ outT, int* __restrict__ outR) {
    __shared__ int hist[256];
    __shared__ unsigned sprefix;
    __shared__ int skrem;
    int tid = threadIdx.x;
    if (tid == 0) { sprefix = 0u; skrem = k; }
    for (int pass = 3; pass >= 0; --pass) {
        __syncthreads();
        for (int i = tid; i < 256; i += blockDim.x) hist[i] = 0;
        __syncthreads();
        unsigned pref = sprefix;
        int shift = (pass + 1) * 8;
        for (int i = tid; i < n; i += blockDim.x) {
            unsigned kk = key[i];
            bool match = ((unsigned long long)kk >> shift) == ((unsigned long long)pref >> shift);
            if (match) atomicAdd(&hist[(kk >> (pass * 8)) & 0xFF], 1);
        }
        __syncthreads();
        if (tid == 0) {
            int krem = skrem;
            int cum = 0; int d = 0;
            for (int b = 255; b >= 0; --b) {
                if (cum + hist[b] >= krem) { d = b; break; }
                cum += hist[b];
            }
            sprefix |= ((unsigned)d) << (pass * 8);
            skrem = krem - cum;
        }
    }
    __syncthreads();
    if (tid == 0) { *outT = sprefix; *outR = skrem; }
}

__global__ void k_select(const unsigned* __restrict__ key, const unsigned* __restrict__ pT,
                         const int* __restrict__ pR, int* __restrict__ nidx,
                         int* __restrict__ sel, int n) {
    unsigned T = *pT; int r = *pR;
    __shared__ int run_sel, run_eq;
    if (threadIdx.x == 0) { run_sel = 0; run_eq = 0; }
    __syncthreads();
    for (int base = 0; base < n; base += 1024) {
        int i = base + threadIdx.x;
        unsigned kk = (i < n) ? key[i] : 0u;
        int eq = (i < n && kk == T) ? 1 : 0;
        int gt = (i < n && kk > T) ? 1 : 0;
        int eq_tot; int eq_ex = block_scan_excl_1024(eq, eq_tot);
        int re = run_eq;
        int sf = gt | (eq & (((re + eq_ex) < r) ? 1 : 0));
        int s_tot; int s_ex = block_scan_excl_1024(sf, s_tot);
        int rs = run_sel;
        if (i < n) {
            if (sf) { int slot = rs + s_ex; nidx[i] = slot; sel[slot] = i; }
            else nidx[i] = -1;
        }
        __syncthreads();
        if (threadIdx.x == 0) { run_sel = rs + s_tot; run_eq = re + eq_tot; }
        __syncthreads();
    }
}

// ---------------- compact pooled edges ----------------
__global__ void k_compact(const int* __restrict__ src, const int* __restrict__ dst,
                          const int* __restrict__ nidx, int* __restrict__ pvs,
                          int* __restrict__ pvd, int* __restrict__ pcount, int E) {
    int e = blockIdx.x * blockDim.x + threadIdx.x;
    if (e >= E) return;
    int vs = nidx[src[e]], vd = nidx[dst[e]];
    if (vs >= 0 && vd >= 0) {
        int slot = atomicAdd(pcount, 1);
        if (slot < PCAP) { pvs[slot] = vs; pvd[slot] = vd; }
    }
}

// ---------------- entire pooled pipeline in one block, LDS-resident ----------------
__global__ __launch_bounds__(1024)
void k_pooled2(const int* __restrict__ pvs, const int* __restrict__ pvd,
               const int* __restrict__ pcount, const int* __restrict__ sel,
               const float* __restrict__ xc, const float* __restrict__ score,
               const float* __restrict__ x, const float* __restrict__ Wp,
               const float* __restrict__ bp, int2* __restrict__ gcsr,
               float* __restrict__ pacc_out, float* __restrict__ selpos) {
    __shared__ float bufA[2 * KSEL];         // 24 KB (T buffers / build scratch)
    __shared__ float bufB[2 * KSEL];         // 24 KB
    __shared__ int   rowstart[KSEL + 1];     // 12 KB
    __shared__ int   s_run;
    const int tid = threadIdx.x, NT = 1024;
    const int pE = min(*pcount, PCAP);

    // --- build phase (overlays: cnt_src/cnt_dst in bufB, dinvp in bufA) ---
    int* cnt_src = (int*)bufB;
    int* cnt_dst = ((int*)bufB) + KSEL;
    float* dinvp = bufA;
    for (int j = tid; j < KSEL; j += NT) { cnt_src[j] = 0; cnt_dst[j] = 0; }
    __syncthreads();
    for (int e = tid; e < pE; e += NT) {
        atomicAdd(&cnt_src[pvs[e]], 1);
        atomicAdd(&cnt_dst[pvd[e]], 1);
    }
    __syncthreads();
    for (int j = tid; j < KSEL; j += NT) {
        int c = cnt_src[j];
        dinvp[j] = c > 0 ? rsqrtf((float)c) : 0.0f;
    }
    // scan cnt_dst -> rowstart
    if (tid == 0) s_run = 0;
    __syncthreads();
    for (int base = 0; base < KSEL; base += NT) {
        int i = base + tid;
        int v = (i < KSEL) ? cnt_dst[i] : 0;
        int tot; int ex = block_scan_excl_1024(v, tot);
        int r = s_run;
        if (i < KSEL) rowstart[i] = r + ex;
        __syncthreads();
        if (tid == 0) s_run += tot;
        __syncthreads();
    }
    if (tid == 0) rowstart[KSEL] = s_run;
    // cursor reuses cnt_dst
    for (int j = tid; j < KSEL; j += NT) cnt_dst[j] = 0;
    __syncthreads();
    for (int e = tid; e < pE; e += NT) {
        int vs = pvs[e], vd = pvd[e];
        int pos = atomicAdd(&cnt_dst[vd], 1);
        float w = -dinvp[vs] * dinvp[vd];
        gcsr[rowstart[vd] + pos] = make_int2(vs, __float_as_int(w));
    }
    __syncthreads();

    // --- init: T0 = xp1 into bufA; pacc in registers ---
    const float bp0 = bp[0], bp1 = bp[1];
    float accA[3], accB[3];
#pragma unroll
    for (int r = 0; r < 3; ++r) {
        int j = tid + r * NT;
        accA[r] = 0.f; accB[r] = 0.f;
        if (j < KSEL) {
            int i = sel[j];
            float s = score[i];
            float a = xc[2 * i] * s, b = xc[2 * i + 1] * s;
            bufA[2 * j] = a; bufA[2 * j + 1] = b;
            accA[r] = bp0 + a * Wp[0] + b * Wp[2];
            accB[r] = bp1 + a * Wp[1] + b * Wp[3];
            selpos[2 * j] = x[i * FIN + 14];
            selpos[2 * j + 1] = x[i * FIN + 15];
        }
    }
    __syncthreads();

    // --- 7 hops, ping-pong LDS buffers ---
    for (int k = 1; k < KHOP; ++k) {
        float* rb = (k & 1) ? bufA : bufB;
        float* wb = (k & 1) ? bufB : bufA;
        float w0 = Wp[k * 4 + 0], w1 = Wp[k * 4 + 1];
        float w2 = Wp[k * 4 + 2], w3 = Wp[k * 4 + 3];
#pragma unroll
        for (int r = 0; r < 3; ++r) {
            int j = tid + r * NT;
            if (j < KSEL) {
                float pa = 0.f, pb = 0.f;
                int e0 = rowstart[j], e1 = rowstart[j + 1];
                for (int e = e0; e < e1; ++e) {
                    int2 ew = gcsr[e];
                    float w = __int_as_float(ew.y);
                    pa = fmaf(w, rb[2 * ew.x], pa);
                    pb = fmaf(w, rb[2 * ew.x + 1], pb);
                }
                if (k >= 2) {
                    pa = 2.f * pa - wb[2 * j];
                    pb = 2.f * pb - wb[2 * j + 1];
                }
                wb[2 * j] = pa; wb[2 * j + 1] = pb;
                accA[r] = fmaf(pa, w0, fmaf(pb, w2, accA[r]));
                accB[r] = fmaf(pa, w1, fmaf(pb, w3, accB[r]));
            }
        }
        __syncthreads();
    }

    // --- write pacc ---
#pragma unroll
    for (int r = 0; r < 3; ++r) {
        int j = tid + r * NT;
        if (j < KSEL) {
            pacc_out[2 * j] = accA[r];
            pacc_out[2 * j + 1] = accB[r];
        }
    }
}

// ---------------- nearest pooled node: chunked partial argmin via packed u64 ----------------
__global__ void k_near_part(const float* __restrict__ x, const float* __restrict__ selpos,
                            unsigned long long* __restrict__ best, int n) {
    __shared__ float2 sp[CHUNK];
    const int j0 = blockIdx.y * CHUNK;
    for (int j = threadIdx.x; j < CHUNK; j += blockDim.x)
        sp[j] = ((const float2*)selpos)[j0 + j];
    __syncthreads();
    int i = blockIdx.x * blockDim.x + threadIdx.x;
    if (i >= n) return;
    float px = x[i * FIN + 14], py = x[i * FIN + 15];
    float bd = 3.4e38f; int bj = 0;
#pragma unroll 2
    for (int j = 0; j < CHUNK; ++j) {
        float dx = px - sp[j].x, dy = py - sp[j].y;
        float d = fmaf(dx, dx, dy * dy);
        if (d < bd) { bd = d; bj = j0 + j; }
    }
    unsigned long long pk = ((unsigned long long)__float_as_uint(bd) << 32) | (unsigned)bj;
    atomicMin(&best[i], pk);
}

// ---------------- final linear (74 -> 10) ----------------
__global__ void k_final(const float* __restrict__ x1, const float* __restrict__ x2,
                        const float* __restrict__ xp2, const unsigned long long* __restrict__ best,
                        const float* __restrict__ W3, const float* __restrict__ b3,
                        float* __restrict__ o, int n) {
    __shared__ float sW[740], sb[10];
    for (int i = threadIdx.x; i < 740; i += blockDim.x) sW[i] = W3[i];
    if (threadIdx.x < 10) sb[threadIdx.x] = b3[threadIdx.x];
    __syncthreads();
    int t = blockIdx.x * blockDim.x + threadIdx.x;
    if (t >= n * 10) return;
    int i = t / 10, c = t - 10 * (t / 10);
    float s = sb[c];
    const float* r1 = &x1[i * H1];
#pragma unroll
    for (int f = 0; f < H1; ++f) s = fmaf(r1[f], sW[f * 10 + c], s);
    const float* r2 = &x2[i * H2];
#pragma unroll
    for (int f = 0; f < H2; ++f) s = fmaf(r2[f], sW[(H1 + f) * 10 + c], s);
    int m = (int)(best[i] & 0xFFFFFFFFull);
    s = fmaf(xp2[m * 2],     sW[720 + c], s);
    s = fmaf(xp2[m * 2 + 1], sW[730 + c], s);
    o[t] = s;
}

// =====================================================================
extern "C" void kernel_launch(void* const* d_in, const int* in_sizes, int n_in,
                              void* d_out, int out_size, void* d_ws, size_t ws_size,
                              hipStream_t stream) {
    const float* x   = (const float*)d_in[0];
    const int*   ei  = (const int*)d_in[1];
    const int*   src = ei;
    const int*   dst = ei + NE;
    const float* W1  = (const float*)d_in[2];
    const float* b1  = (const float*)d_in[3];
    const float* W2  = (const float*)d_in[4];
    const float* b2  = (const float*)d_in[5];
    const float* g1  = (const float*)d_in[6];
    const float* be1 = (const float*)d_in[7];
    const float* g2  = (const float*)d_in[8];
    const float* be2 = (const float*)d_in[9];
    const float* Wc  = (const float*)d_in[10];
    const float* bc  = (const float*)d_in[11];
    const float* pw  = (const float*)d_in[12];
    const float* Wp  = (const float*)d_in[13];
    const float* bp  = (const float*)d_in[14];
    const float* W3  = (const float*)d_in[15];
    const float* b3  = (const float*)d_in[16];
    float* out = (float*)d_out;

    // ---- workspace layout ----
    char* w = (char*)d_ws;
    auto alloc = [&](size_t bytes) -> void* {
        void* p = (void*)w;
        w += (bytes + 255) & ~(size_t)255;
        return p;
    };
    int*   cnt_src  = (int*)alloc(NN * 4);
    int*   cnt_dst  = (int*)alloc(NN * 4);
    float* dinv     = (float*)alloc(NN * 4);
    int*   rowstart = (int*)alloc((NN + 1) * 4);
    int*   cursor   = (int*)alloc(NN * 4);
    int2*  csr      = (int2*)alloc((size_t)NE * 8);
    float* B1    = (float*)alloc((size_t)NN * H1 * 4);
    float* B2    = (float*)alloc((size_t)NN * H1 * 4);
    float* B3    = (float*)alloc((size_t)NN * H1 * 4);
    float* acc   = (float*)alloc((size_t)NN * H1 * 4);
    float* x1    = (float*)alloc((size_t)NN * H1 * 4);
    float* x2    = (float*)alloc((size_t)NN * H2 * 4);
    float* xc    = (float*)alloc((size_t)NN * 2 * 4);
    float* score = (float*)alloc(NN * 4);
    float* stats = (float*)alloc(2 * H1 * 4);
    unsigned* key   = (unsigned*)alloc(NN * 4);
    int* nidx       = (int*)alloc(NN * 4);
    int* sel        = (int*)alloc(KSEL * 4);
    unsigned long long* best = (unsigned long long*)alloc(NN * 8);
    unsigned* Tptr  = (unsigned*)alloc(4);
    int* Rptr       = (int*)alloc(4);
    int* pvs        = (int*)alloc(PCAP * 4);
    int* pvd        = (int*)alloc(PCAP * 4);
    int* pcount     = (int*)alloc(4);
    int2* gcsr      = (int2*)alloc((size_t)PCAP * 8);
    float* pacc     = (float*)alloc(KSEL * 2 * 4);
    float* selpos   = (float*)alloc(KSEL * 2 * 4);

    const int NBK = (NN + 63) / 64;

    // ---- degree + CSR build ----
    hipMemsetAsync(cnt_src, 0, NN * 4, stream);
    hipMemsetAsync(cnt_dst, 0, NN * 4, stream);
    hipMemsetAsync(cursor, 0, NN * 4, stream);
    hipMemsetAsync(pcount, 0, 4, stream);
    hipMemsetAsync(best, 0xFF, NN * 8, stream);
    k_count2<<<nb(NE), TPB, 0, stream>>>(src, dst, cnt_src, cnt_dst, NE);
    k_dinv2<<<nb(NN), TPB, 0, stream>>>(cnt_src, dinv, NN);
    k_scan<<<1, 1024, 0, stream>>>(cnt_dst, rowstart, NN);
    k_fill<<<nb(NE), TPB, 0, stream>>>(src, dst, dinv, rowstart, cursor, csr, NE);

    // ---- conv1: K=8, 16 -> 36 ----
    {
        k_gemm_init<FIN, H1><<<nb((long long)NN * H1), TPB, 0, stream>>>(x, W1, b1, acc, NN);
        float* rot[3] = {B1, B2, B3};
        k_prop_gemm<FIN, H1, 64><<<NBK, 64 * (FIN / 4), 0, stream>>>(
            rowstart, csr, x, nullptr, W1 + FIN * H1, B1, acc, NN, 1);
        const float* t_prev = x; const float* t_cur = B1;
        for (int kk = 2; kk < KHOP; ++kk) {
            float* o = rot[(kk - 1) % 3];
            k_prop_gemm<FIN, H1, 64><<<NBK, 64 * (FIN / 4), 0, stream>>>(
                rowstart, csr, t_cur, t_prev, W1 + kk * FIN * H1, o, acc, NN, 0);
            t_prev = t_cur; t_cur = o;
        }
        hipMemsetAsync(stats, 0, 2 * H1 * 4, stream);
        k_colstats<H1><<<120, TPB, 0, stream>>>(acc, stats, NN);
        k_bn<H1><<<nb((long long)NN * H1), TPB, 0, stream>>>(acc, stats, g1, be1, x1, NN);
    }

    // ---- conv2: K=8, 36 -> 36 ----
    {
        k_gemm_init<H1, H2><<<nb((long long)NN * H2), TPB, 0, stream>>>(x1, W2, b2, acc, NN);
        float* rot[3] = {B1, B2, B3};
        k_prop_gemm<H1, H2, 64><<<NBK, 64 * (H1 / 4), 0, stream>>>(
            rowstart, csr, x1, nullptr, W2 + H1 * H2, B1, acc, NN, 1);
        const float* t_prev = x1; const float* t_cur = B1;
        for (int kk = 2; kk < KHOP; ++kk) {
            float* o = rot[(kk - 1) % 3];
            k_prop_gemm<H1, H2, 64><<<NBK, 64 * (H1 / 4), 0, stream>>>(
                rowstart, csr, t_cur, t_prev, W2 + kk * H1 * H2, o, acc, NN, 0);
            t_prev = t_cur; t_cur = o;
        }
        hipMemsetAsync(stats, 0, 2 * H2 * 4, stream);
        k_colstats<H2><<<120, TPB, 0, stream>>>(acc, stats, NN);
        k_bn<H2><<<nb((long long)NN * H2), TPB, 0, stream>>>(acc, stats, g2, be2, x2, NN);
    }

    // ---- xc, score, key ----
    k_xc_score<<<nb(NN), TPB, 0, stream>>>(x1, Wc, bc, pw, xc, score, key, NN);

    // ---- top-k selection ----
    k_kth<<<1, 1024, 0, stream>>>(key, NN, KSEL, Tptr, Rptr);
    k_select<<<1, 1024, 0, stream>>>(key, Tptr, Rptr, nidx, sel, NN);

    // ---- pooled graph: compact edges, then single-block LDS pipeline ----
    k_compact<<<nb(NE), TPB, 0, stream>>>(src, dst, nidx, pvs, pvd, pcount, NE);
    k_pooled2<<<1, 1024, 0, stream>>>(pvs, pvd, pcount, sel, xc, score, x, Wp, bp,
                                      gcsr, pacc, selpos);

    // ---- nearest pooled node (chunked), final linear ----
    {
        dim3 g(nb(NN), NCHUNK);
        k_near_part<<<g, TPB, 0, stream>>>(x, selpos, best, NN);
    }
    k_final<<<nb((long long)NN * 10), TPB, 0, stream>>>(x1, x2, pacc, best, W3, b3, out, NN);
}